// Round 13
// baseline (18848.753 us; speedup 1.0000x reference)
//
#include <hip/hip_runtime.h>
#include <math.h>

// Seq2seq LSTM: 5-layer stack, HID=80, 336 enc + 48 dec steps, batch 512.
// R13: R12 (256 blocks x NB=2, proven 4.10ms) + encoder inner loop rebuilt:
//      4-deep weight register ring (named sets, NO v_mov copies; load lead
//      ~3 chunks covers L2 latency) + depth-2 h ping-pong + l0 12-chunk trim.
//      Decoder / prep / fallback byte-identical to R12.
#define LAYERS  5
#define HID     80
#define GATES   320
#define INDIM   4
#define BATCH   512
#define SEQLEN  336
#define PREDLEN 48
#define TOT     (SEQLEN + PREDLEN)
#define NB      4            // fallback kernel's batch/block
#define ENB     2            // main kernel's batch/block
#define NTHR    800
#define NSUP    (SEQLEN + LAYERS - 1)   // 340 supersteps

#define BSTR 96
#define LSTR (ENB * BSTR)        // 192
#define HTOT (LAYERS * LSTR)     // 960 floats per parity buffer
#define CSZ  (LAYERS * ENB * HID)// 800

// ws (float4): [enc 64000][dec 64000][bias_e 400][bias_d 400][w0dec 1280]
//  enc (R9 SoA): idx ((wl*20+i)*4 + j)*160 + lt   lt=em*2+emat
//  dec:          idx ((l*10+i)*4 + j)*320 + lt    lt=dm*4+dmat*2+dkh
#define NE4     64000
#define ND4     64000
#define OFF_D   NE4
#define OFF_BE  (NE4 + ND4)      // 128000
#define OFF_BD  (OFF_BE + 400)   // 128400
#define OFF_W0D (OFF_BD + 400)   // 128800
#define NWS4    (OFF_W0D + 1280) // 130080
#define WS_NEED ((size_t)NWS4 * 16)
#define NPREP   NWS4

__device__ __forceinline__ float sigm(float v) { return 1.0f / (1.0f + __expf(-v)); }
__device__ __forceinline__ float tanh_fast(float v) {
    return 1.0f - 2.0f / (1.0f + __expf(2.0f * v));
}
__device__ __forceinline__ float gate_act(float v, bool tg) {
    const float e = __expf(tg ? 2.0f * v : -v);
    const float r = 1.0f / (1.0f + e);
    return tg ? 1.0f - 2.0f * r : r;
}
__device__ __forceinline__ float rs4(float v0, float v1, float v2, float v3, int q) {
    float u = (q & 1) ? v1 : v0;
    float s = (q & 1) ? v0 : v1;
    u += __shfl_xor(s, 1);
    float u2 = (q & 1) ? v3 : v2;
    float s2 = (q & 1) ? v2 : v3;
    u2 += __shfl_xor(s2, 1);
    float k = (q & 2) ? u2 : u;
    float s3 = (q & 2) ? u : u2;
    k += __shfl_xor(s3, 2);
    return k;
}

// 8 float4-FMAs into a[4][2]
#define FMA8(W, H)                                                               \
    do {                                                                         \
        _Pragma("unroll")                                                        \
        for (int _j = 0; _j < 4; ++_j) {                                         \
            _Pragma("unroll")                                                    \
            for (int _b = 0; _b < 2; ++_b)                                       \
                a[_j][_b] += (W)[_j].x * (H)[_b].x + (W)[_j].y * (H)[_b].y       \
                           + (W)[_j].z * (H)[_b].z + (W)[_j].w * (H)[_b].w;      \
        }                                                                        \
    } while (0)

// encoder ring helpers: weight set load (chunk base WQ + f4-offset OFS),
// h pair load (chunk index C off hbase)
#define LDW(SET, WQ, OFS)                                                        \
    do {                                                                         \
        _Pragma("unroll")                                                        \
        for (int _j = 0; _j < 4; ++_j) (SET)[_j] = (WQ)[(OFS) + _j * 160];       \
    } while (0)
#define LDH(SET, C)                                                              \
    do {                                                                         \
        (SET)[0] = *(const float4*)(hbase + 4 * (C));                            \
        (SET)[1] = *(const float4*)(hbase + BSTR + 4 * (C));                     \
    } while (0)

// ================= prep: pack weights/biases (R12 verbatim) =================
__global__ void prep_pack(const float* __restrict__ eW0,  const float* __restrict__ eWih,
                          const float* __restrict__ eWhh, const float* __restrict__ ebih,
                          const float* __restrict__ ebhh,
                          const float* __restrict__ dW0,  const float* __restrict__ dWih,
                          const float* __restrict__ dWhh, const float* __restrict__ dbih,
                          const float* __restrict__ dbhh, float* __restrict__ ws)
{
    const int gid = blockIdx.x * 256 + threadIdx.x;
    float4* w4 = (float4*)ws;
    if (gid < NE4) {                    // encoder wavefront layout
        const int lt = gid % 160;
        const int j  = (gid / 160) & 3;
        const int i  = (gid / 640) % 20;
        const int l  = gid / 12800;
        const int m = lt >> 1, mat = lt & 1;
        const int row = m + 80 * j;
        float4 v = make_float4(0.f, 0.f, 0.f, 0.f);
        if (l > 0) {
            v = mat ? *(const float4*)&eWih[((size_t)(l - 1) * GATES + row) * HID + 4 * i]
                    : *(const float4*)&eWhh[((size_t)l * GATES + row) * HID + 4 * i];
        } else if (!mat) {
            if (i < 10) v = *(const float4*)&eWhh[(size_t)row * HID + 4 * i];
        } else {
            if (i < 10)       v = *(const float4*)&eWhh[(size_t)row * HID + 40 + 4 * i];
            else if (i == 10) v = *(const float4*)&eW0[row * INDIM];
        }
        w4[gid] = v;
        return;
    }
    int g2 = gid - NE4;
    if (g2 < ND4) {                     // decoder k-half layout
        const int lt = g2 % 320;
        const int j  = (g2 / 320) & 3;
        const int i  = (g2 / 1280) % 10;
        const int l  = g2 / 12800;
        const int dm = lt >> 2, dmat = (lt >> 1) & 1, dkh = lt & 1;
        const int row = dm + 80 * j;
        const int k0  = dkh * 40 + 4 * i;
        float4 v = make_float4(0.f, 0.f, 0.f, 0.f);
        if (l == 0) {
            if (!dmat) v = *(const float4*)&dWhh[(size_t)row * HID + k0];
        } else {
            v = dmat ? *(const float4*)&dWih[((size_t)(l - 1) * GATES + row) * HID + k0]
                     : *(const float4*)&dWhh[((size_t)l * GATES + row) * HID + k0];
        }
        w4[OFF_D + g2] = v;
        return;
    }
    int g3 = g2 - ND4;
    if (g3 < 800) {                     // biases: [ctx][l][m] f4 over gates
        const int ctx = g3 / 400, r = g3 % 400;
        const int l = r / 80, m = r % 80;
        const float* bi = ctx ? dbih : ebih;
        const float* bh = ctx ? dbhh : ebhh;
        float4 v;
        v.x = bi[l * GATES + m]       + bh[l * GATES + m];
        v.y = bi[l * GATES + m + 80]  + bh[l * GATES + m + 80];
        v.z = bi[l * GATES + m + 160] + bh[l * GATES + m + 160];
        v.w = bi[l * GATES + m + 240] + bh[l * GATES + m + 240];
        w4[OFF_BE + g3] = v;
        return;
    }
    int g4 = g3 - 800;
    if (g4 < 1280) {                    // decoder W0 rows
        const int lt = g4 % 320, j = g4 / 320;
        const int dm = lt >> 2;
        w4[OFF_W0D + g4] = *(const float4*)&dW0[(dm + 80 * j) * INDIM];
    }
}

// ================= main persistent kernel =================
__global__ __launch_bounds__(NTHR) void lstm_main(
    const float* __restrict__ x,   const float* __restrict__ ff,
    const float* __restrict__ fcW, const float* __restrict__ fcb,
    const float* __restrict__ ws,  float* __restrict__ out)
{
    __shared__ __align__(16) float hA[HTOT];     // parity-0 h (+x slots)
    __shared__ __align__(16) float hB[HTOT];     // parity-1 h
    __shared__ __align__(16) float cS[CSZ];
    __shared__ __align__(16) float sx[ENB][4];   // decoder input

    const float4* w4  = (const float4*)ws;
    const float4* w4d = w4 + OFF_D;
    const float4* b4e = w4 + OFF_BE;
    const float4* b4d = w4 + OFF_BD;
    const float4* w0d = w4 + OFF_W0D;

    const int tid = threadIdx.x;
    const int b0  = blockIdx.x * ENB;

    for (int i = tid; i < HTOT; i += NTHR) { hA[i] = 0.0f; hB[i] = 0.0f; }
    for (int i = tid; i < CSZ; i += NTHR) cS[i] = 0.0f;
    if (tid < ENB)     // prestage x(0) into hB x-slots (prv of superstep 0)
        *(float4*)&hB[tid * BSTR + 80] = *(const float4*)&x[((size_t)(b0 + tid) * SEQLEN) * INDIM];
    __syncthreads();

    // ---------------- encoder: wavefront supersteps ----------------
    const int wl   = tid / 160;          // layer worker
    const int lt   = tid % 160;
    const int em   = lt >> 1;            // unit
    const int emat = lt & 1;             // matrix half
    const int nq   = (wl == 0) ? 2 : 4;  // quad iterations (l0: 12 chunks, else 20)

    #pragma unroll 1
    for (int s = 0; s < NSUP; ++s) {
        float* cur = (s & 1) ? hB : hA;
        float* prv = (s & 1) ? hA : hB;
        const int t = s - wl;

        if (tid < ENB && s + 1 < SEQLEN)  // stage x(s+1) into cur x-slot
            *(float4*)&cur[tid * BSTR + 80] =
                *(const float4*)&x[((size_t)(b0 + tid) * SEQLEN + (s + 1)) * INDIM];

        if (t >= 0 && t < SEQLEN) {
            const float* hbase = emat ? (wl ? prv + (wl - 1) * LSTR : prv + 40)
                                      : prv + wl * LSTR;
            const float4* wq = w4 + (size_t)wl * 12800 + lt;

            // prologue: weight ring chunks 0..3, h chunks 0..1
            float4 w0[4], w1[4], w2[4], w3[4], ha[2], hb[2];
            LDW(w0, wq, 0);
            LDW(w1, wq, 640);
            LDW(w2, wq, 1280);
            LDW(w3, wq, 1920);
            LDH(ha, 0);
            LDH(hb, 1);

            float a[4][2];
            #pragma unroll
            for (int j = 0; j < 4; ++j) { a[j][0] = 0.0f; a[j][1] = 0.0f; }

            #pragma unroll 1
            for (int q4 = 0; q4 < nq; ++q4) {    // chunks 4q..4q+3; ring +4
                const int c = 4 * q4;
                FMA8(w0, ha); LDW(w0, wq, 2560); LDH(ha, c + 2);
                FMA8(w1, hb); LDW(w1, wq, 3200); LDH(hb, c + 3);
                FMA8(w2, ha); LDW(w2, wq, 3840); LDH(ha, c + 4);
                FMA8(w3, hb); LDW(w3, wq, 4480); LDH(hb, c + 5);
                wq += 2560;
            }
            {   // tail: chunks 4nq..4nq+3 (w ring full; h needs last two)
                const int c = 4 * nq;
                FMA8(w0, ha); LDH(ha, c + 2);
                FMA8(w1, hb); LDH(hb, c + 3);
                FMA8(w2, ha);
                FMA8(w3, hb);
            }

            // mat fold: lane keeps batch emat
            float sA[4];
            #pragma unroll
            for (int j = 0; j < 4; ++j)
                sA[j] = a[j][emat] + __shfl_xor(a[j][emat ^ 1], 1);

            const float4 bv = b4e[wl * 80 + em];
            const float gi = sigm(sA[0] + bv.x);
            const float gf = sigm(sA[1] + bv.y);
            const float gg = tanh_fast(sA[2] + bv.z);
            const float go = sigm(sA[3] + bv.w);
            const int ci = wl * (ENB * HID) + emat * HID + em;
            const float cn = gf * cS[ci] + gi * gg;
            cS[ci] = cn;
            cur[wl * LSTR + emat * BSTR + em] = go * tanh_fast(cn);
        }
        __syncthreads();
    }

    // ---------------- transition: gather final h into hB; stage dec input ----
    for (int i = tid; i < 2 * LSTR; i += NTHR) {
        const int l = (i < LSTR) ? 1 : 3;
        const int off = i % LSTR;
        hB[l * LSTR + off] = hA[l * LSTR + off];
    }
    if (tid < ENB * INDIM)
        sx[tid >> 2][tid & 3] =
            x[((size_t)(b0 + (tid >> 2)) * SEQLEN + (SEQLEN - 1)) * INDIM + (tid & 3)];
    __syncthreads();

    // ---------------- decoder: 320 threads (R12 verbatim) ----------
    const int dm   = tid >> 2;
    const int dmat = (tid >> 1) & 1;
    const int dkh  = tid & 1;

    #pragma unroll 1
    for (int t = SEQLEN; t < TOT; ++t) {
        float* cur = (t & 1) ? hB : hA;
        float* prv = (t & 1) ? hA : hB;

        #pragma unroll 1
        for (int l = 0; l < LAYERS; ++l) {
            if (tid < 320) {
                float a[4][2];
                #pragma unroll
                for (int j = 0; j < 4; ++j) { a[j][0] = 0.0f; a[j][1] = 0.0f; }

                if (l == 0 && dmat) {
                    if (dkh == 0) {        // W0 . x (both batches)
                        const float4 xv0 = *(const float4*)&sx[0][0];
                        const float4 xv1 = *(const float4*)&sx[1][0];
                        #pragma unroll
                        for (int j = 0; j < 4; ++j) {
                            const float4 w0v = w0d[j * 320 + tid];
                            a[j][0] += w0v.x * xv0.x + w0v.y * xv0.y + w0v.z * xv0.z + w0v.w * xv0.w;
                            a[j][1] += w0v.x * xv1.x + w0v.y * xv1.y + w0v.z * xv1.z + w0v.w * xv1.w;
                        }
                    }
                } else {
                    const float* hb = (dmat ? cur + (l - 1) * LSTR : prv + l * LSTR)
                                      + dkh * 40;
                    const float4* wp = w4d + (size_t)l * 12800 + tid;
                    float4 wv[4];
                    wv[0] = wp[0]; wv[1] = wp[320]; wv[2] = wp[640]; wv[3] = wp[960];

                    #pragma unroll 1
                    for (int i = 0; i < 9; ++i) {
                        const float4* np = wp + 1280;
                        float4 nv[4];
                        nv[0] = np[0]; nv[1] = np[320]; nv[2] = np[640]; nv[3] = np[960];
                        float4 hv[2];
                        hv[0] = *(const float4*)(hb + 4 * i);
                        hv[1] = *(const float4*)(hb + BSTR + 4 * i);
                        FMA8(wv, hv);
                        #pragma unroll
                        for (int j = 0; j < 4; ++j) wv[j] = nv[j];
                        wp = np;
                    }
                    {   // tail i = 9
                        float4 hv[2];
                        hv[0] = *(const float4*)(hb + 36);
                        hv[1] = *(const float4*)(hb + BSTR + 36);
                        FMA8(wv, hv);
                    }
                }

                // fold: k-half (xor1) then mat (xor2)
                float s[4];
                #pragma unroll
                for (int j = 0; j < 4; ++j)
                    s[j] = a[j][dkh] + __shfl_xor(a[j][dkh ^ 1], 1);
                #pragma unroll
                for (int j = 0; j < 4; ++j)
                    s[j] += __shfl_xor(s[j], 2);

                const float4 bv = b4d[l * 80 + dm];
                float act0, act1;
                if (!dmat) { act0 = sigm(s[0] + bv.x);      act1 = sigm(s[1] + bv.y); }
                else       { act0 = tanh_fast(s[2] + bv.z); act1 = sigm(s[3] + bv.w); }
                const float o0 = __shfl_xor(act0, 2);
                const float o1 = __shfl_xor(act1, 2);
                if (!dmat) {
                    const float gi = act0, gf = act1, gg = o0, go = o1;
                    const int ci = l * (ENB * HID) + dkh * HID + dm;
                    const float cn = gf * cS[ci] + gi * gg;
                    cS[ci] = cn;
                    cur[l * LSTR + dkh * BSTR + dm] = go * tanh_fast(cn);
                }
            }
            __syncthreads();
        }

        const int td = t - SEQLEN;
        if (tid < ENB) {                // pred + feedback
            float s = fcb[0];
            const float* hvp = cur + 4 * LSTR + tid * BSTR;
            #pragma unroll
            for (int jj = 0; jj < HID; jj += 4) {
                const float4 wv4 = *(const float4*)&fcW[jj];
                const float4 h4  = *(const float4*)&hvp[jj];
                s += wv4.x * h4.x + wv4.y * h4.y + wv4.z * h4.z + wv4.w * h4.w;
            }
            out[(size_t)(b0 + tid) * PREDLEN + td] = s;
            sx[tid][0] = s;
        } else if (tid >= 64 && tid < 64 + ENB * 3) {
            const int qd = tid - 64;
            const int nb = qd / 3, k = qd % 3;
            sx[nb][k + 1] = ff[((size_t)(b0 + nb) * PREDLEN + td) * 3 + k];
        }
        __syncthreads();
    }
}

// ================= fallback (R5 kernel, proven) if ws too small =================
#define FQK 20
#define FCHUNK(WPTR, HPTR, I)                                                    \
    do {                                                                         \
        const float4 wA = *(const float4*)((WPTR) + 4 * (I));                    \
        const float4 wB = *(const float4*)((WPTR) + HID + 4 * (I));              \
        const float* _hb = (HPTR);                                               \
        const float4 h0 = *(const float4*)(_hb + 0 * HID + 4 * (I));             \
        const float4 h1 = *(const float4*)(_hb + 1 * HID + 4 * (I));             \
        const float4 h2 = *(const float4*)(_hb + 2 * HID + 4 * (I));             \
        const float4 h3 = *(const float4*)(_hb + 3 * HID + 4 * (I));             \
        a00 += wA.x * h0.x + wA.y * h0.y + wA.z * h0.z + wA.w * h0.w;            \
        a01 += wA.x * h1.x + wA.y * h1.y + wA.z * h1.z + wA.w * h1.w;            \
        a02 += wA.x * h2.x + wA.y * h2.y + wA.z * h2.z + wA.w * h2.w;            \
        a03 += wA.x * h3.x + wA.y * h3.y + wA.z * h3.z + wA.w * h3.w;            \
        a10 += wB.x * h0.x + wB.y * h0.y + wB.z * h0.z + wB.w * h0.w;            \
        a11 += wB.x * h1.x + wB.y * h1.y + wB.z * h1.z + wB.w * h1.w;            \
        a12 += wB.x * h2.x + wB.y * h2.y + wB.z * h2.z + wB.w * h2.w;            \
        a13 += wB.x * h3.x + wB.y * h3.y + wB.z * h3.z + wB.w * h3.w;            \
    } while (0)

__global__ __launch_bounds__(640) void lstm_fb(
    const float* __restrict__ x,    const float* __restrict__ ff,
    const float* __restrict__ eW0,  const float* __restrict__ eWih,
    const float* __restrict__ eWhh, const float* __restrict__ ebih,
    const float* __restrict__ ebhh,
    const float* __restrict__ dW0,  const float* __restrict__ dWih,
    const float* __restrict__ dWhh, const float* __restrict__ dbih,
    const float* __restrict__ dbhh,
    const float* __restrict__ fcW,  const float* __restrict__ fcb,
    float* __restrict__ out)
{
    __shared__ __align__(16) float sh[LAYERS][NB][HID];
    __shared__ __align__(16) float sc[LAYERS][NB][HID];
    __shared__ __align__(16) float sg[NB][GATES + 1];
    __shared__ __align__(16) float sx[NB][INDIM];

    const int tid = threadIdx.x;
    const int q   = tid & 3;
    const int mm  = tid >> 2;
    const int r0  = 2 * mm;
    const int b0  = blockIdx.x * NB;

    for (int i = tid; i < LAYERS * NB * HID; i += 640) {
        (&sh[0][0][0])[i] = 0.0f;
        (&sc[0][0][0])[i] = 0.0f;
    }
    const bool is_tg = (r0 >= 2 * HID) && (r0 < 3 * HID);
    const int  unb = tid / HID, uj = tid % HID;

    float bs[2][LAYERS][2];
    #pragma unroll
    for (int l = 0; l < LAYERS; ++l) {
        bs[0][l][0] = ebih[l * GATES + r0]     + ebhh[l * GATES + r0];
        bs[0][l][1] = ebih[l * GATES + r0 + 1] + ebhh[l * GATES + r0 + 1];
        bs[1][l][0] = dbih[l * GATES + r0]     + dbhh[l * GATES + r0];
        bs[1][l][1] = dbih[l * GATES + r0 + 1] + dbhh[l * GATES + r0 + 1];
    }
    const float w0e0 = eW0[r0 * INDIM + q], w0e1 = eW0[(r0 + 1) * INDIM + q];
    const float w0d0 = dW0[r0 * INDIM + q], w0d1 = dW0[(r0 + 1) * INDIM + q];

    for (int t = 0; t < TOT; ++t) {
        const bool enc = (t < SEQLEN);
        const float* Wih = enc ? eWih : dWih;
        const float* Whh = enc ? eWhh : dWhh;
        if (enc && tid < NB * INDIM) {
            const int nb = tid / INDIM, k = tid % INDIM;
            sx[nb][k] = x[((size_t)(b0 + nb) * SEQLEN + t) * INDIM + k];
        }
        __syncthreads();
        #pragma unroll
        for (int l = 0; l < LAYERS; ++l) {
            float a00 = 0.f, a01 = 0.f, a02 = 0.f, a03 = 0.f;
            float a10 = 0.f, a11 = 0.f, a12 = 0.f, a13 = 0.f;
            {
                const float* wp = Whh + ((size_t)l * GATES + r0) * HID + q * FQK;
                const float* hp = &sh[l][0][q * FQK];
                #pragma unroll
                for (int i = 0; i < FQK / 4; ++i) FCHUNK(wp, hp, i);
            }
            if (l == 0) {
                const float wa = enc ? w0e0 : w0d0;
                const float wb = enc ? w0e1 : w0d1;
                a00 += wa * sx[0][q];  a01 += wa * sx[1][q];
                a02 += wa * sx[2][q];  a03 += wa * sx[3][q];
                a10 += wb * sx[0][q];  a11 += wb * sx[1][q];
                a12 += wb * sx[2][q];  a13 += wb * sx[3][q];
            } else {
                const float* wp = Wih + ((size_t)(l - 1) * GATES + r0) * HID + q * FQK;
                const float* hp = &sh[l - 1][0][q * FQK];
                #pragma unroll
                for (int i = 0; i < FQK / 4; ++i) FCHUNK(wp, hp, i);
            }
            const float s0 = rs4(a00, a01, a02, a03, q);
            const float s1 = rs4(a10, a11, a12, a13, q);
            const float bias0 = enc ? bs[0][l][0] : bs[1][l][0];
            const float bias1 = enc ? bs[0][l][1] : bs[1][l][1];
            sg[q][r0]     = gate_act(s0 + bias0, is_tg);
            sg[q][r0 + 1] = gate_act(s1 + bias1, is_tg);
            __syncthreads();
            if (tid < NB * HID) {
                const float iv = sg[unb][uj];
                const float fv = sg[unb][uj + HID];
                const float gv = sg[unb][uj + 2 * HID];
                const float ov = sg[unb][uj + 3 * HID];
                const float cn = fv * sc[l][unb][uj] + iv * gv;
                const float hn = ov * tanh_fast(cn);
                sc[l][unb][uj] = cn;
                sh[l][unb][uj] = hn;
            }
            __syncthreads();
        }
        if (!enc) {
            const int td = t - SEQLEN;
            if (tid < NB) {
                float s = fcb[0];
                #pragma unroll
                for (int j = 0; j < HID; j += 4) {
                    const float4 wv = *(const float4*)&fcW[j];
                    const float4 hv = *(const float4*)&sh[LAYERS - 1][tid][j];
                    s += wv.x * hv.x + wv.y * hv.y + wv.z * hv.z + wv.w * hv.w;
                }
                out[(size_t)(b0 + tid) * PREDLEN + td] = s;
                sx[tid][0] = s;
            } else if (tid >= 64 && tid < 64 + NB * 3) {
                const int qd = tid - 64;
                const int nb = qd / 3, k = qd % 3;
                sx[nb][k + 1] = ff[((size_t)(b0 + nb) * PREDLEN + td) * 3 + k];
            }
        }
    }
}

extern "C" void kernel_launch(void* const* d_in, const int* in_sizes, int n_in,
                              void* d_out, int out_size, void* d_ws, size_t ws_size,
                              hipStream_t stream) {
    const float* x    = (const float*)d_in[0];
    const float* ff   = (const float*)d_in[1];
    const float* eW0  = (const float*)d_in[2];
    const float* eWih = (const float*)d_in[3];
    const float* eWhh = (const float*)d_in[4];
    const float* ebih = (const float*)d_in[5];
    const float* ebhh = (const float*)d_in[6];
    const float* dW0  = (const float*)d_in[7];
    const float* dWih = (const float*)d_in[8];
    const float* dWhh = (const float*)d_in[9];
    const float* dbih = (const float*)d_in[10];
    const float* dbhh = (const float*)d_in[11];
    const float* fcW  = (const float*)d_in[12];
    const float* fcb  = (const float*)d_in[13];

    if (ws_size >= WS_NEED) {
        prep_pack<<<(NPREP + 255) / 256, 256, 0, stream>>>(
            eW0, eWih, eWhh, ebih, ebhh, dW0, dWih, dWhh, dbih, dbhh, (float*)d_ws);
        lstm_main<<<BATCH / ENB, NTHR, 0, stream>>>(
            x, ff, fcW, fcb, (const float*)d_ws, (float*)d_out);
    } else {
        lstm_fb<<<BATCH / NB, 640, 0, stream>>>(
            x, ff, eW0, eWih, eWhh, ebih, ebhh,
            dW0, dWih, dWhh, dbih, dbhh, fcW, fcb, (float*)d_out);
    }
}

// Round 14
// 3813.400 us; speedup vs baseline: 4.9428x; 4.9428x over previous
//
#include <hip/hip_runtime.h>
#include <math.h>

// Seq2seq LSTM: 5-layer stack, HID=80, 336 enc + 48 dec steps, batch 512.
// R14: R12 (256 blocks x ENB=2, proven 4.10ms) with encoder inner loop as
//      2-deep named ping-pong (NO v_mov copies; R11-proven compilable shape,
//      now in the issue-exposed full-chip regime) + l0 12-chunk trim.
//      4-deep ring (R13) spilled -> abandoned. Decoder/prep/fallback = R12.
#define LAYERS  5
#define HID     80
#define GATES   320
#define INDIM   4
#define BATCH   512
#define SEQLEN  336
#define PREDLEN 48
#define TOT     (SEQLEN + PREDLEN)
#define NB      4            // fallback kernel's batch/block
#define ENB     2            // main kernel's batch/block
#define NTHR    800
#define NSUP    (SEQLEN + LAYERS - 1)   // 340 supersteps

#define BSTR 96
#define LSTR (ENB * BSTR)        // 192
#define HTOT (LAYERS * LSTR)     // 960 floats per parity buffer
#define CSZ  (LAYERS * ENB * HID)// 800

// ws (float4): [enc 64000][dec 64000][bias_e 400][bias_d 400][w0dec 1280]
//  enc (R9 SoA): idx ((wl*20+i)*4 + j)*160 + lt   lt=em*2+emat
//  dec:          idx ((l*10+i)*4 + j)*320 + lt    lt=dm*4+dmat*2+dkh
#define NE4     64000
#define ND4     64000
#define OFF_D   NE4
#define OFF_BE  (NE4 + ND4)      // 128000
#define OFF_BD  (OFF_BE + 400)   // 128400
#define OFF_W0D (OFF_BD + 400)   // 128800
#define NWS4    (OFF_W0D + 1280) // 130080
#define WS_NEED ((size_t)NWS4 * 16)
#define NPREP   NWS4

__device__ __forceinline__ float sigm(float v) { return 1.0f / (1.0f + __expf(-v)); }
__device__ __forceinline__ float tanh_fast(float v) {
    return 1.0f - 2.0f / (1.0f + __expf(2.0f * v));
}
__device__ __forceinline__ float gate_act(float v, bool tg) {
    const float e = __expf(tg ? 2.0f * v : -v);
    const float r = 1.0f / (1.0f + e);
    return tg ? 1.0f - 2.0f * r : r;
}
__device__ __forceinline__ float rs4(float v0, float v1, float v2, float v3, int q) {
    float u = (q & 1) ? v1 : v0;
    float s = (q & 1) ? v0 : v1;
    u += __shfl_xor(s, 1);
    float u2 = (q & 1) ? v3 : v2;
    float s2 = (q & 1) ? v2 : v3;
    u2 += __shfl_xor(s2, 1);
    float k = (q & 2) ? u2 : u;
    float s3 = (q & 2) ? u : u2;
    k += __shfl_xor(s3, 2);
    return k;
}

// 8 float4-FMAs into a[4][2]
#define FMA8(W, H)                                                               \
    do {                                                                         \
        _Pragma("unroll")                                                        \
        for (int _j = 0; _j < 4; ++_j) {                                         \
            _Pragma("unroll")                                                    \
            for (int _b = 0; _b < 2; ++_b)                                       \
                a[_j][_b] += (W)[_j].x * (H)[_b].x + (W)[_j].y * (H)[_b].y       \
                           + (W)[_j].z * (H)[_b].z + (W)[_j].w * (H)[_b].w;      \
        }                                                                        \
    } while (0)

// encoder helpers: weight set load (f4-offset OFS from wq), h pair (chunk C)
#define LDW(SET, OFS)                                                            \
    do {                                                                         \
        _Pragma("unroll")                                                        \
        for (int _j = 0; _j < 4; ++_j) (SET)[_j] = wq[(OFS) + _j * 160];         \
    } while (0)
#define LDH(SET, C)                                                              \
    do {                                                                         \
        (SET)[0] = *(const float4*)(hbase + 4 * (C));                            \
        (SET)[1] = *(const float4*)(hbase + BSTR + 4 * (C));                     \
    } while (0)

// ================= prep: pack weights/biases (R12 verbatim) =================
__global__ void prep_pack(const float* __restrict__ eW0,  const float* __restrict__ eWih,
                          const float* __restrict__ eWhh, const float* __restrict__ ebih,
                          const float* __restrict__ ebhh,
                          const float* __restrict__ dW0,  const float* __restrict__ dWih,
                          const float* __restrict__ dWhh, const float* __restrict__ dbih,
                          const float* __restrict__ dbhh, float* __restrict__ ws)
{
    const int gid = blockIdx.x * 256 + threadIdx.x;
    float4* w4 = (float4*)ws;
    if (gid < NE4) {                    // encoder wavefront layout
        const int lt = gid % 160;
        const int j  = (gid / 160) & 3;
        const int i  = (gid / 640) % 20;
        const int l  = gid / 12800;
        const int m = lt >> 1, mat = lt & 1;
        const int row = m + 80 * j;
        float4 v = make_float4(0.f, 0.f, 0.f, 0.f);
        if (l > 0) {
            v = mat ? *(const float4*)&eWih[((size_t)(l - 1) * GATES + row) * HID + 4 * i]
                    : *(const float4*)&eWhh[((size_t)l * GATES + row) * HID + 4 * i];
        } else if (!mat) {
            if (i < 10) v = *(const float4*)&eWhh[(size_t)row * HID + 4 * i];
        } else {
            if (i < 10)       v = *(const float4*)&eWhh[(size_t)row * HID + 40 + 4 * i];
            else if (i == 10) v = *(const float4*)&eW0[row * INDIM];
        }
        w4[gid] = v;
        return;
    }
    int g2 = gid - NE4;
    if (g2 < ND4) {                     // decoder k-half layout
        const int lt = g2 % 320;
        const int j  = (g2 / 320) & 3;
        const int i  = (g2 / 1280) % 10;
        const int l  = g2 / 12800;
        const int dm = lt >> 2, dmat = (lt >> 1) & 1, dkh = lt & 1;
        const int row = dm + 80 * j;
        const int k0  = dkh * 40 + 4 * i;
        float4 v = make_float4(0.f, 0.f, 0.f, 0.f);
        if (l == 0) {
            if (!dmat) v = *(const float4*)&dWhh[(size_t)row * HID + k0];
        } else {
            v = dmat ? *(const float4*)&dWih[((size_t)(l - 1) * GATES + row) * HID + k0]
                     : *(const float4*)&dWhh[((size_t)l * GATES + row) * HID + k0];
        }
        w4[OFF_D + g2] = v;
        return;
    }
    int g3 = g2 - ND4;
    if (g3 < 800) {                     // biases: [ctx][l][m] f4 over gates
        const int ctx = g3 / 400, r = g3 % 400;
        const int l = r / 80, m = r % 80;
        const float* bi = ctx ? dbih : ebih;
        const float* bh = ctx ? dbhh : ebhh;
        float4 v;
        v.x = bi[l * GATES + m]       + bh[l * GATES + m];
        v.y = bi[l * GATES + m + 80]  + bh[l * GATES + m + 80];
        v.z = bi[l * GATES + m + 160] + bh[l * GATES + m + 160];
        v.w = bi[l * GATES + m + 240] + bh[l * GATES + m + 240];
        w4[OFF_BE + g3] = v;
        return;
    }
    int g4 = g3 - 800;
    if (g4 < 1280) {                    // decoder W0 rows
        const int lt = g4 % 320, j = g4 / 320;
        const int dm = lt >> 2;
        w4[OFF_W0D + g4] = *(const float4*)&dW0[(dm + 80 * j) * INDIM];
    }
}

// ================= main persistent kernel =================
__global__ __launch_bounds__(NTHR) void lstm_main(
    const float* __restrict__ x,   const float* __restrict__ ff,
    const float* __restrict__ fcW, const float* __restrict__ fcb,
    const float* __restrict__ ws,  float* __restrict__ out)
{
    __shared__ __align__(16) float hA[HTOT];     // parity-0 h (+x slots)
    __shared__ __align__(16) float hB[HTOT];     // parity-1 h
    __shared__ __align__(16) float cS[CSZ];
    __shared__ __align__(16) float sx[ENB][4];   // decoder input

    const float4* w4  = (const float4*)ws;
    const float4* w4d = w4 + OFF_D;
    const float4* b4e = w4 + OFF_BE;
    const float4* b4d = w4 + OFF_BD;
    const float4* w0d = w4 + OFF_W0D;

    const int tid = threadIdx.x;
    const int b0  = blockIdx.x * ENB;

    for (int i = tid; i < HTOT; i += NTHR) { hA[i] = 0.0f; hB[i] = 0.0f; }
    for (int i = tid; i < CSZ; i += NTHR) cS[i] = 0.0f;
    if (tid < ENB)     // prestage x(0) into hB x-slots (prv of superstep 0)
        *(float4*)&hB[tid * BSTR + 80] = *(const float4*)&x[((size_t)(b0 + tid) * SEQLEN) * INDIM];
    __syncthreads();

    // ---------------- encoder: wavefront supersteps ----------------
    const int wl    = tid / 160;          // layer worker
    const int lt    = tid % 160;
    const int em    = lt >> 1;            // unit
    const int emat  = lt & 1;             // matrix half
    const int npair = (wl == 0) ? 5 : 9;  // chunk pairs; total = 2*npair+2

    #pragma unroll 1
    for (int s = 0; s < NSUP; ++s) {
        float* cur = (s & 1) ? hB : hA;
        float* prv = (s & 1) ? hA : hB;
        const int t = s - wl;

        if (tid < ENB && s + 1 < SEQLEN)  // stage x(s+1) into cur x-slot
            *(float4*)&cur[tid * BSTR + 80] =
                *(const float4*)&x[((size_t)(b0 + tid) * SEQLEN + (s + 1)) * INDIM];

        if (t >= 0 && t < SEQLEN) {
            const float* hbase = emat ? (wl ? prv + (wl - 1) * LSTR : prv + 40)
                                      : prv + wl * LSTR;
            const float4* wq = w4 + (size_t)wl * 12800 + lt;

            // 2-deep ping-pong: A=even chunks, B=odd; loads land in place
            float4 wA[4], wB[4], ha[2], hb[2];
            LDW(wA, 0);
            LDW(wB, 640);
            LDH(ha, 0);
            LDH(hb, 1);

            float a[4][2];
            #pragma unroll
            for (int j = 0; j < 4; ++j) { a[j][0] = 0.0f; a[j][1] = 0.0f; }

            #pragma unroll 1
            for (int ii = 0; ii < npair; ++ii) {   // consume 2ii,2ii+1; load +2,+3
                const int c = 2 * ii;
                FMA8(wA, ha);
                LDW(wA, 1280);
                LDH(ha, c + 2);
                FMA8(wB, hb);
                LDW(wB, 1920);
                LDH(hb, c + 3);
                wq += 1280;
            }
            FMA8(wA, ha);                          // chunk 2*npair
            FMA8(wB, hb);                          // chunk 2*npair+1

            // mat fold: lane keeps batch emat
            float sA[4];
            #pragma unroll
            for (int j = 0; j < 4; ++j)
                sA[j] = a[j][emat] + __shfl_xor(a[j][emat ^ 1], 1);

            const float4 bv = b4e[wl * 80 + em];
            const float gi = sigm(sA[0] + bv.x);
            const float gf = sigm(sA[1] + bv.y);
            const float gg = tanh_fast(sA[2] + bv.z);
            const float go = sigm(sA[3] + bv.w);
            const int ci = wl * (ENB * HID) + emat * HID + em;
            const float cn = gf * cS[ci] + gi * gg;
            cS[ci] = cn;
            cur[wl * LSTR + emat * BSTR + em] = go * tanh_fast(cn);
        }
        __syncthreads();
    }

    // ---------------- transition: gather final h into hB; stage dec input ----
    for (int i = tid; i < 2 * LSTR; i += NTHR) {
        const int l = (i < LSTR) ? 1 : 3;
        const int off = i % LSTR;
        hB[l * LSTR + off] = hA[l * LSTR + off];
    }
    if (tid < ENB * INDIM)
        sx[tid >> 2][tid & 3] =
            x[((size_t)(b0 + (tid >> 2)) * SEQLEN + (SEQLEN - 1)) * INDIM + (tid & 3)];
    __syncthreads();

    // ---------------- decoder: 320 threads (R12 verbatim) ----------
    const int dm   = tid >> 2;
    const int dmat = (tid >> 1) & 1;
    const int dkh  = tid & 1;

    #pragma unroll 1
    for (int t = SEQLEN; t < TOT; ++t) {
        float* cur = (t & 1) ? hB : hA;
        float* prv = (t & 1) ? hA : hB;

        #pragma unroll 1
        for (int l = 0; l < LAYERS; ++l) {
            if (tid < 320) {
                float a[4][2];
                #pragma unroll
                for (int j = 0; j < 4; ++j) { a[j][0] = 0.0f; a[j][1] = 0.0f; }

                if (l == 0 && dmat) {
                    if (dkh == 0) {        // W0 . x (both batches)
                        const float4 xv0 = *(const float4*)&sx[0][0];
                        const float4 xv1 = *(const float4*)&sx[1][0];
                        #pragma unroll
                        for (int j = 0; j < 4; ++j) {
                            const float4 w0v = w0d[j * 320 + tid];
                            a[j][0] += w0v.x * xv0.x + w0v.y * xv0.y + w0v.z * xv0.z + w0v.w * xv0.w;
                            a[j][1] += w0v.x * xv1.x + w0v.y * xv1.y + w0v.z * xv1.z + w0v.w * xv1.w;
                        }
                    }
                } else {
                    const float* hb = (dmat ? cur + (l - 1) * LSTR : prv + l * LSTR)
                                      + dkh * 40;
                    const float4* wp = w4d + (size_t)l * 12800 + tid;
                    float4 wv[4];
                    wv[0] = wp[0]; wv[1] = wp[320]; wv[2] = wp[640]; wv[3] = wp[960];

                    #pragma unroll 1
                    for (int i = 0; i < 9; ++i) {
                        const float4* np = wp + 1280;
                        float4 nv[4];
                        nv[0] = np[0]; nv[1] = np[320]; nv[2] = np[640]; nv[3] = np[960];
                        float4 hv[2];
                        hv[0] = *(const float4*)(hb + 4 * i);
                        hv[1] = *(const float4*)(hb + BSTR + 4 * i);
                        FMA8(wv, hv);
                        #pragma unroll
                        for (int j = 0; j < 4; ++j) wv[j] = nv[j];
                        wp = np;
                    }
                    {   // tail i = 9
                        float4 hv[2];
                        hv[0] = *(const float4*)(hb + 36);
                        hv[1] = *(const float4*)(hb + BSTR + 36);
                        FMA8(wv, hv);
                    }
                }

                // fold: k-half (xor1) then mat (xor2)
                float s[4];
                #pragma unroll
                for (int j = 0; j < 4; ++j)
                    s[j] = a[j][dkh] + __shfl_xor(a[j][dkh ^ 1], 1);
                #pragma unroll
                for (int j = 0; j < 4; ++j)
                    s[j] += __shfl_xor(s[j], 2);

                const float4 bv = b4d[l * 80 + dm];
                float act0, act1;
                if (!dmat) { act0 = sigm(s[0] + bv.x);      act1 = sigm(s[1] + bv.y); }
                else       { act0 = tanh_fast(s[2] + bv.z); act1 = sigm(s[3] + bv.w); }
                const float o0 = __shfl_xor(act0, 2);
                const float o1 = __shfl_xor(act1, 2);
                if (!dmat) {
                    const float gi = act0, gf = act1, gg = o0, go = o1;
                    const int ci = l * (ENB * HID) + dkh * HID + dm;
                    const float cn = gf * cS[ci] + gi * gg;
                    cS[ci] = cn;
                    cur[l * LSTR + dkh * BSTR + dm] = go * tanh_fast(cn);
                }
            }
            __syncthreads();
        }

        const int td = t - SEQLEN;
        if (tid < ENB) {                // pred + feedback
            float s = fcb[0];
            const float* hvp = cur + 4 * LSTR + tid * BSTR;
            #pragma unroll
            for (int jj = 0; jj < HID; jj += 4) {
                const float4 wv4 = *(const float4*)&fcW[jj];
                const float4 h4  = *(const float4*)&hvp[jj];
                s += wv4.x * h4.x + wv4.y * h4.y + wv4.z * h4.z + wv4.w * h4.w;
            }
            out[(size_t)(b0 + tid) * PREDLEN + td] = s;
            sx[tid][0] = s;
        } else if (tid >= 64 && tid < 64 + ENB * 3) {
            const int qd = tid - 64;
            const int nb = qd / 3, k = qd % 3;
            sx[nb][k + 1] = ff[((size_t)(b0 + nb) * PREDLEN + td) * 3 + k];
        }
        __syncthreads();
    }
}

// ================= fallback (R5 kernel, proven) if ws too small =================
#define FQK 20
#define FCHUNK(WPTR, HPTR, I)                                                    \
    do {                                                                         \
        const float4 wA = *(const float4*)((WPTR) + 4 * (I));                    \
        const float4 wB = *(const float4*)((WPTR) + HID + 4 * (I));              \
        const float* _hb = (HPTR);                                               \
        const float4 h0 = *(const float4*)(_hb + 0 * HID + 4 * (I));             \
        const float4 h1 = *(const float4*)(_hb + 1 * HID + 4 * (I));             \
        const float4 h2 = *(const float4*)(_hb + 2 * HID + 4 * (I));             \
        const float4 h3 = *(const float4*)(_hb + 3 * HID + 4 * (I));             \
        a00 += wA.x * h0.x + wA.y * h0.y + wA.z * h0.z + wA.w * h0.w;            \
        a01 += wA.x * h1.x + wA.y * h1.y + wA.z * h1.z + wA.w * h1.w;            \
        a02 += wA.x * h2.x + wA.y * h2.y + wA.z * h2.z + wA.w * h2.w;            \
        a03 += wA.x * h3.x + wA.y * h3.y + wA.z * h3.z + wA.w * h3.w;            \
        a10 += wB.x * h0.x + wB.y * h0.y + wB.z * h0.z + wB.w * h0.w;            \
        a11 += wB.x * h1.x + wB.y * h1.y + wB.z * h1.z + wB.w * h1.w;            \
        a12 += wB.x * h2.x + wB.y * h2.y + wB.z * h2.z + wB.w * h2.w;            \
        a13 += wB.x * h3.x + wB.y * h3.y + wB.z * h3.z + wB.w * h3.w;            \
    } while (0)

__global__ __launch_bounds__(640) void lstm_fb(
    const float* __restrict__ x,    const float* __restrict__ ff,
    const float* __restrict__ eW0,  const float* __restrict__ eWih,
    const float* __restrict__ eWhh, const float* __restrict__ ebih,
    const float* __restrict__ ebhh,
    const float* __restrict__ dW0,  const float* __restrict__ dWih,
    const float* __restrict__ dWhh, const float* __restrict__ dbih,
    const float* __restrict__ dbhh,
    const float* __restrict__ fcW,  const float* __restrict__ fcb,
    float* __restrict__ out)
{
    __shared__ __align__(16) float sh[LAYERS][NB][HID];
    __shared__ __align__(16) float sc[LAYERS][NB][HID];
    __shared__ __align__(16) float sg[NB][GATES + 1];
    __shared__ __align__(16) float sx[NB][INDIM];

    const int tid = threadIdx.x;
    const int q   = tid & 3;
    const int mm  = tid >> 2;
    const int r0  = 2 * mm;
    const int b0  = blockIdx.x * NB;

    for (int i = tid; i < LAYERS * NB * HID; i += 640) {
        (&sh[0][0][0])[i] = 0.0f;
        (&sc[0][0][0])[i] = 0.0f;
    }
    const bool is_tg = (r0 >= 2 * HID) && (r0 < 3 * HID);
    const int  unb = tid / HID, uj = tid % HID;

    float bs[2][LAYERS][2];
    #pragma unroll
    for (int l = 0; l < LAYERS; ++l) {
        bs[0][l][0] = ebih[l * GATES + r0]     + ebhh[l * GATES + r0];
        bs[0][l][1] = ebih[l * GATES + r0 + 1] + ebhh[l * GATES + r0 + 1];
        bs[1][l][0] = dbih[l * GATES + r0]     + dbhh[l * GATES + r0];
        bs[1][l][1] = dbih[l * GATES + r0 + 1] + dbhh[l * GATES + r0 + 1];
    }
    const float w0e0 = eW0[r0 * INDIM + q], w0e1 = eW0[(r0 + 1) * INDIM + q];
    const float w0d0 = dW0[r0 * INDIM + q], w0d1 = dW0[(r0 + 1) * INDIM + q];

    for (int t = 0; t < TOT; ++t) {
        const bool enc = (t < SEQLEN);
        const float* Wih = enc ? eWih : dWih;
        const float* Whh = enc ? eWhh : dWhh;
        if (enc && tid < NB * INDIM) {
            const int nb = tid / INDIM, k = tid % INDIM;
            sx[nb][k] = x[((size_t)(b0 + nb) * SEQLEN + t) * INDIM + k];
        }
        __syncthreads();
        #pragma unroll
        for (int l = 0; l < LAYERS; ++l) {
            float a00 = 0.f, a01 = 0.f, a02 = 0.f, a03 = 0.f;
            float a10 = 0.f, a11 = 0.f, a12 = 0.f, a13 = 0.f;
            {
                const float* wp = Whh + ((size_t)l * GATES + r0) * HID + q * FQK;
                const float* hp = &sh[l][0][q * FQK];
                #pragma unroll
                for (int i = 0; i < FQK / 4; ++i) FCHUNK(wp, hp, i);
            }
            if (l == 0) {
                const float wa = enc ? w0e0 : w0d0;
                const float wb = enc ? w0e1 : w0d1;
                a00 += wa * sx[0][q];  a01 += wa * sx[1][q];
                a02 += wa * sx[2][q];  a03 += wa * sx[3][q];
                a10 += wb * sx[0][q];  a11 += wb * sx[1][q];
                a12 += wb * sx[2][q];  a13 += wb * sx[3][q];
            } else {
                const float* wp = Wih + ((size_t)(l - 1) * GATES + r0) * HID + q * FQK;
                const float* hp = &sh[l - 1][0][q * FQK];
                #pragma unroll
                for (int i = 0; i < FQK / 4; ++i) FCHUNK(wp, hp, i);
            }
            const float s0 = rs4(a00, a01, a02, a03, q);
            const float s1 = rs4(a10, a11, a12, a13, q);
            const float bias0 = enc ? bs[0][l][0] : bs[1][l][0];
            const float bias1 = enc ? bs[0][l][1] : bs[1][l][1];
            sg[q][r0]     = gate_act(s0 + bias0, is_tg);
            sg[q][r0 + 1] = gate_act(s1 + bias1, is_tg);
            __syncthreads();
            if (tid < NB * HID) {
                const float iv = sg[unb][uj];
                const float fv = sg[unb][uj + HID];
                const float gv = sg[unb][uj + 2 * HID];
                const float ov = sg[unb][uj + 3 * HID];
                const float cn = fv * sc[l][unb][uj] + iv * gv;
                const float hn = ov * tanh_fast(cn);
                sc[l][unb][uj] = cn;
                sh[l][unb][uj] = hn;
            }
            __syncthreads();
        }
        if (!enc) {
            const int td = t - SEQLEN;
            if (tid < NB) {
                float s = fcb[0];
                #pragma unroll
                for (int j = 0; j < HID; j += 4) {
                    const float4 wv = *(const float4*)&fcW[j];
                    const float4 hv = *(const float4*)&sh[LAYERS - 1][tid][j];
                    s += wv.x * hv.x + wv.y * hv.y + wv.z * hv.z + wv.w * hv.w;
                }
                out[(size_t)(b0 + tid) * PREDLEN + td] = s;
                sx[tid][0] = s;
            } else if (tid >= 64 && tid < 64 + NB * 3) {
                const int qd = tid - 64;
                const int nb = qd / 3, k = qd % 3;
                sx[nb][k + 1] = ff[((size_t)(b0 + nb) * PREDLEN + td) * 3 + k];
            }
        }
    }
}

extern "C" void kernel_launch(void* const* d_in, const int* in_sizes, int n_in,
                              void* d_out, int out_size, void* d_ws, size_t ws_size,
                              hipStream_t stream) {
    const float* x    = (const float*)d_in[0];
    const float* ff   = (const float*)d_in[1];
    const float* eW0  = (const float*)d_in[2];
    const float* eWih = (const float*)d_in[3];
    const float* eWhh = (const float*)d_in[4];
    const float* ebih = (const float*)d_in[5];
    const float* ebhh = (const float*)d_in[6];
    const float* dW0  = (const float*)d_in[7];
    const float* dWih = (const float*)d_in[8];
    const float* dWhh = (const float*)d_in[9];
    const float* dbih = (const float*)d_in[10];
    const float* dbhh = (const float*)d_in[11];
    const float* fcW  = (const float*)d_in[12];
    const float* fcb  = (const float*)d_in[13];

    if (ws_size >= WS_NEED) {
        prep_pack<<<(NPREP + 255) / 256, 256, 0, stream>>>(
            eW0, eWih, eWhh, ebih, ebhh, dW0, dWih, dWhh, dbih, dbhh, (float*)d_ws);
        lstm_main<<<BATCH / ENB, NTHR, 0, stream>>>(
            x, ff, fcW, fcb, (const float*)d_ws, (float*)d_out);
    } else {
        lstm_fb<<<BATCH / NB, 640, 0, stream>>>(
            x, ff, eW0, eWih, eWhh, ebih, ebhh,
            dW0, dWih, dWhh, dbih, dbhh, fcW, fcb, (float*)d_out);
    }
}

// Round 15
// 3707.194 us; speedup vs baseline: 5.0844x; 1.0286x over previous
//
#include <hip/hip_runtime.h>
#include <hip/hip_fp16.h>
#include <math.h>

// Seq2seq LSTM: 5-layer stack, HID=80, 336 enc + 48 dec steps, batch 512.
// R15: R14 (3.81ms, no spill) + ENCODER WEIGHTS IN FP16 (decoder fp32).
//      Superstep is bound by the per-CU vector-return path (~64 B/cy):
//      1.02 MB fp32 weights/CU/superstep -> 512 KB fp16. Compute stays fp32
//      (v_cvt_f32_f16 full-rate before the same FMA8). 2-deep ping-pong +
//      l0 trim kept; decoder/prep-dec/transition/fallback = R12/R14 verbatim.
#define LAYERS  5
#define HID     80
#define GATES   320
#define INDIM   4
#define BATCH   512
#define SEQLEN  336
#define PREDLEN 48
#define TOT     (SEQLEN + PREDLEN)
#define NB      4            // fallback kernel's batch/block
#define ENB     2            // main kernel's batch/block
#define NTHR    800
#define NSUP    (SEQLEN + LAYERS - 1)   // 340 supersteps

#define BSTR 96
#define LSTR (ENB * BSTR)        // 192
#define HTOT (LAYERS * LSTR)     // 960 floats per parity buffer
#define CSZ  (LAYERS * ENB * HID)// 800

// ws (16B units): [enc-f16 32000][dec-f32 64000][bias_e 400][bias_d 400][w0dec 1280]
//  enc-f16: uint4[((wl*20+i)*2 + p)*160 + lt]  lt=em*2+emat, p=gate-pair
//           holds 8 halves: gates {2p,2p+1} x k-chunk i (4 halves each)
//           source floats identical to R14's enc layout (incl. W0 @ l0/mat1/i10)
//  dec (R12): f4[((l*10+i)*4 + j)*320 + lt]    lt=dm*4+dmat*2+dkh
#define NE16    32000
#define ND4     64000
#define OFF_D   NE16             // 32000
#define OFF_BE  (NE16 + ND4)     // 96000
#define OFF_BD  (OFF_BE + 400)   // 96400
#define OFF_W0D (OFF_BD + 400)   // 96800
#define NWS4    (OFF_W0D + 1280) // 98080
#define WS_NEED ((size_t)NWS4 * 16)
#define NPREP   NWS4

__device__ __forceinline__ float sigm(float v) { return 1.0f / (1.0f + __expf(-v)); }
__device__ __forceinline__ float tanh_fast(float v) {
    return 1.0f - 2.0f / (1.0f + __expf(2.0f * v));
}
__device__ __forceinline__ float gate_act(float v, bool tg) {
    const float e = __expf(tg ? 2.0f * v : -v);
    const float r = 1.0f / (1.0f + e);
    return tg ? 1.0f - 2.0f * r : r;
}
__device__ __forceinline__ float rs4(float v0, float v1, float v2, float v3, int q) {
    float u = (q & 1) ? v1 : v0;
    float s = (q & 1) ? v0 : v1;
    u += __shfl_xor(s, 1);
    float u2 = (q & 1) ? v3 : v2;
    float s2 = (q & 1) ? v2 : v3;
    u2 += __shfl_xor(s2, 1);
    float k = (q & 2) ? u2 : u;
    float s3 = (q & 2) ? u : u2;
    k += __shfl_xor(s3, 2);
    return k;
}

__device__ __forceinline__ unsigned h2bits(__half2 h) {
    union { __half2 h; unsigned u; } c; c.h = h; return c.u;
}
__device__ __forceinline__ float2 bits2f2(unsigned u) {
    union { unsigned u; __half2 h; } c; c.u = u; return __half22float2(c.h);
}

// 8 float4-FMAs into a[4][2]
#define FMA8(W, H)                                                               \
    do {                                                                         \
        _Pragma("unroll")                                                        \
        for (int _j = 0; _j < 4; ++_j) {                                         \
            _Pragma("unroll")                                                    \
            for (int _b = 0; _b < 2; ++_b)                                       \
                a[_j][_b] += (W)[_j].x * (H)[_b].x + (W)[_j].y * (H)[_b].y       \
                           + (W)[_j].z * (H)[_b].z + (W)[_j].w * (H)[_b].w;      \
        }                                                                        \
    } while (0)

// unpack 16 halves (2 uint4) -> float4 wf[4] (gates 0..3, k-chunk)
#define CVT8(WF, U0, U1)                                                         \
    do {                                                                         \
        float2 _a = bits2f2((U0).x), _b = bits2f2((U0).y);                       \
        (WF)[0] = make_float4(_a.x, _a.y, _b.x, _b.y);                           \
        _a = bits2f2((U0).z); _b = bits2f2((U0).w);                              \
        (WF)[1] = make_float4(_a.x, _a.y, _b.x, _b.y);                           \
        _a = bits2f2((U1).x); _b = bits2f2((U1).y);                              \
        (WF)[2] = make_float4(_a.x, _a.y, _b.x, _b.y);                           \
        _a = bits2f2((U1).z); _b = bits2f2((U1).w);                              \
        (WF)[3] = make_float4(_a.x, _a.y, _b.x, _b.y);                           \
    } while (0)

#define LDH(SET, C)                                                              \
    do {                                                                         \
        (SET)[0] = *(const float4*)(hbase + 4 * (C));                            \
        (SET)[1] = *(const float4*)(hbase + BSTR + 4 * (C));                     \
    } while (0)

// ================= prep: pack weights/biases =================
__global__ void prep_pack(const float* __restrict__ eW0,  const float* __restrict__ eWih,
                          const float* __restrict__ eWhh, const float* __restrict__ ebih,
                          const float* __restrict__ ebhh,
                          const float* __restrict__ dW0,  const float* __restrict__ dWih,
                          const float* __restrict__ dWhh, const float* __restrict__ dbih,
                          const float* __restrict__ dbhh, float* __restrict__ ws)
{
    const int gid = blockIdx.x * 256 + threadIdx.x;
    float4* w4 = (float4*)ws;
    if (gid < NE16) {                   // encoder fp16 layout
        const int lt = gid % 160;
        const int p  = (gid / 160) & 1;
        const int i  = (gid / 320) % 20;
        const int wl = gid / 6400;
        const int m = lt >> 1, mat = lt & 1;
        float4 f[2];
        #pragma unroll
        for (int g = 0; g < 2; ++g) {
            const int j = 2 * p + g;
            const int row = m + 80 * j;
            float4 v = make_float4(0.f, 0.f, 0.f, 0.f);
            if (wl > 0) {
                v = mat ? *(const float4*)&eWih[((size_t)(wl - 1) * GATES + row) * HID + 4 * i]
                        : *(const float4*)&eWhh[((size_t)wl * GATES + row) * HID + 4 * i];
            } else if (!mat) {
                if (i < 10) v = *(const float4*)&eWhh[(size_t)row * HID + 4 * i];
            } else {
                if (i < 10)       v = *(const float4*)&eWhh[(size_t)row * HID + 40 + 4 * i];
                else if (i == 10) v = *(const float4*)&eW0[row * INDIM];
            }
            f[g] = v;
        }
        uint4 u;
        u.x = h2bits(__floats2half2_rn(f[0].x, f[0].y));
        u.y = h2bits(__floats2half2_rn(f[0].z, f[0].w));
        u.z = h2bits(__floats2half2_rn(f[1].x, f[1].y));
        u.w = h2bits(__floats2half2_rn(f[1].z, f[1].w));
        ((uint4*)ws)[gid] = u;
        return;
    }
    int g2 = gid - NE16;
    if (g2 < ND4) {                     // decoder k-half layout (fp32, R12)
        const int lt = g2 % 320;
        const int j  = (g2 / 320) & 3;
        const int i  = (g2 / 1280) % 10;
        const int l  = g2 / 12800;
        const int dm = lt >> 2, dmat = (lt >> 1) & 1, dkh = lt & 1;
        const int row = dm + 80 * j;
        const int k0  = dkh * 40 + 4 * i;
        float4 v = make_float4(0.f, 0.f, 0.f, 0.f);
        if (l == 0) {
            if (!dmat) v = *(const float4*)&dWhh[(size_t)row * HID + k0];
        } else {
            v = dmat ? *(const float4*)&dWih[((size_t)(l - 1) * GATES + row) * HID + k0]
                     : *(const float4*)&dWhh[((size_t)l * GATES + row) * HID + k0];
        }
        w4[OFF_D + g2] = v;
        return;
    }
    int g3 = g2 - ND4;
    if (g3 < 800) {                     // biases: [ctx][l][m] f4 over gates
        const int ctx = g3 / 400, r = g3 % 400;
        const int l = r / 80, m = r % 80;
        const float* bi = ctx ? dbih : ebih;
        const float* bh = ctx ? dbhh : ebhh;
        float4 v;
        v.x = bi[l * GATES + m]       + bh[l * GATES + m];
        v.y = bi[l * GATES + m + 80]  + bh[l * GATES + m + 80];
        v.z = bi[l * GATES + m + 160] + bh[l * GATES + m + 160];
        v.w = bi[l * GATES + m + 240] + bh[l * GATES + m + 240];
        w4[OFF_BE + g3] = v;
        return;
    }
    int g4 = g3 - 800;
    if (g4 < 1280) {                    // decoder W0 rows
        const int lt = g4 % 320, j = g4 / 320;
        const int dm = lt >> 2;
        w4[OFF_W0D + g4] = *(const float4*)&dW0[(dm + 80 * j) * INDIM];
    }
}

// ================= main persistent kernel =================
__global__ __launch_bounds__(NTHR) void lstm_main(
    const float* __restrict__ x,   const float* __restrict__ ff,
    const float* __restrict__ fcW, const float* __restrict__ fcb,
    const float* __restrict__ ws,  float* __restrict__ out)
{
    __shared__ __align__(16) float hA[HTOT];     // parity-0 h (+x slots)
    __shared__ __align__(16) float hB[HTOT];     // parity-1 h
    __shared__ __align__(16) float cS[CSZ];
    __shared__ __align__(16) float sx[ENB][4];   // decoder input

    const uint4*  w16 = (const uint4*)ws;
    const float4* w4d = (const float4*)ws + OFF_D;
    const float4* b4e = (const float4*)ws + OFF_BE;
    const float4* b4d = (const float4*)ws + OFF_BD;
    const float4* w0d = (const float4*)ws + OFF_W0D;

    const int tid = threadIdx.x;
    const int b0  = blockIdx.x * ENB;

    for (int i = tid; i < HTOT; i += NTHR) { hA[i] = 0.0f; hB[i] = 0.0f; }
    for (int i = tid; i < CSZ; i += NTHR) cS[i] = 0.0f;
    if (tid < ENB)     // prestage x(0) into hB x-slots (prv of superstep 0)
        *(float4*)&hB[tid * BSTR + 80] = *(const float4*)&x[((size_t)(b0 + tid) * SEQLEN) * INDIM];
    __syncthreads();

    // ---------------- encoder: wavefront supersteps ----------------
    const int wl    = tid / 160;          // layer worker
    const int lt    = tid % 160;
    const int em    = lt >> 1;            // unit
    const int emat  = lt & 1;             // matrix half
    const int npair = (wl == 0) ? 5 : 9;  // chunk pairs; total = 2*npair+2

    #pragma unroll 1
    for (int s = 0; s < NSUP; ++s) {
        float* cur = (s & 1) ? hB : hA;
        float* prv = (s & 1) ? hA : hB;
        const int t = s - wl;

        if (tid < ENB && s + 1 < SEQLEN)  // stage x(s+1) into cur x-slot
            *(float4*)&cur[tid * BSTR + 80] =
                *(const float4*)&x[((size_t)(b0 + tid) * SEQLEN + (s + 1)) * INDIM];

        if (t >= 0 && t < SEQLEN) {
            const float* hbase = emat ? (wl ? prv + (wl - 1) * LSTR : prv + 40)
                                      : prv + wl * LSTR;
            const uint4* wq = w16 + (size_t)wl * 6400 + lt;

            // 2-deep ping-pong; fp16 weight chunks land in uint4 pairs
            uint4 uA0, uA1, uB0, uB1;
            float4 ha[2], hb[2];
            uA0 = wq[0];   uA1 = wq[160];
            uB0 = wq[320]; uB1 = wq[480];
            LDH(ha, 0);
            LDH(hb, 1);

            float a[4][2];
            #pragma unroll
            for (int j = 0; j < 4; ++j) { a[j][0] = 0.0f; a[j][1] = 0.0f; }

            #pragma unroll 1
            for (int ii = 0; ii < npair; ++ii) {   // consume 2ii,2ii+1; load +2,+3
                const int c = 2 * ii;
                {
                    float4 wf[4];
                    CVT8(wf, uA0, uA1);
                    FMA8(wf, ha);
                }
                uA0 = wq[640]; uA1 = wq[800];
                LDH(ha, c + 2);
                {
                    float4 wf[4];
                    CVT8(wf, uB0, uB1);
                    FMA8(wf, hb);
                }
                uB0 = wq[960]; uB1 = wq[1120];
                LDH(hb, c + 3);
                wq += 640;
            }
            {   // tail: chunks 2*npair, 2*npair+1
                float4 wf[4];
                CVT8(wf, uA0, uA1);
                FMA8(wf, ha);
                CVT8(wf, uB0, uB1);
                FMA8(wf, hb);
            }

            // mat fold: lane keeps batch emat
            float sA[4];
            #pragma unroll
            for (int j = 0; j < 4; ++j)
                sA[j] = a[j][emat] + __shfl_xor(a[j][emat ^ 1], 1);

            const float4 bv = b4e[wl * 80 + em];
            const float gi = sigm(sA[0] + bv.x);
            const float gf = sigm(sA[1] + bv.y);
            const float gg = tanh_fast(sA[2] + bv.z);
            const float go = sigm(sA[3] + bv.w);
            const int ci = wl * (ENB * HID) + emat * HID + em;
            const float cn = gf * cS[ci] + gi * gg;
            cS[ci] = cn;
            cur[wl * LSTR + emat * BSTR + em] = go * tanh_fast(cn);
        }
        __syncthreads();
    }

    // ---------------- transition: gather final h into hB; stage dec input ----
    for (int i = tid; i < 2 * LSTR; i += NTHR) {
        const int l = (i < LSTR) ? 1 : 3;
        const int off = i % LSTR;
        hB[l * LSTR + off] = hA[l * LSTR + off];
    }
    if (tid < ENB * INDIM)
        sx[tid >> 2][tid & 3] =
            x[((size_t)(b0 + (tid >> 2)) * SEQLEN + (SEQLEN - 1)) * INDIM + (tid & 3)];
    __syncthreads();

    // ---------------- decoder: 320 threads (R12 verbatim, fp32) ----------
    const int dm   = tid >> 2;
    const int dmat = (tid >> 1) & 1;
    const int dkh  = tid & 1;

    #pragma unroll 1
    for (int t = SEQLEN; t < TOT; ++t) {
        float* cur = (t & 1) ? hB : hA;
        float* prv = (t & 1) ? hA : hB;

        #pragma unroll 1
        for (int l = 0; l < LAYERS; ++l) {
            if (tid < 320) {
                float a[4][2];
                #pragma unroll
                for (int j = 0; j < 4; ++j) { a[j][0] = 0.0f; a[j][1] = 0.0f; }

                if (l == 0 && dmat) {
                    if (dkh == 0) {        // W0 . x (both batches)
                        const float4 xv0 = *(const float4*)&sx[0][0];
                        const float4 xv1 = *(const float4*)&sx[1][0];
                        #pragma unroll
                        for (int j = 0; j < 4; ++j) {
                            const float4 w0v = w0d[j * 320 + tid];
                            a[j][0] += w0v.x * xv0.x + w0v.y * xv0.y + w0v.z * xv0.z + w0v.w * xv0.w;
                            a[j][1] += w0v.x * xv1.x + w0v.y * xv1.y + w0v.z * xv1.z + w0v.w * xv1.w;
                        }
                    }
                } else {
                    const float* hb = (dmat ? cur + (l - 1) * LSTR : prv + l * LSTR)
                                      + dkh * 40;
                    const float4* wp = w4d + (size_t)l * 12800 + tid;
                    float4 wv[4];
                    wv[0] = wp[0]; wv[1] = wp[320]; wv[2] = wp[640]; wv[3] = wp[960];

                    #pragma unroll 1
                    for (int i = 0; i < 9; ++i) {
                        const float4* np = wp + 1280;
                        float4 nv[4];
                        nv[0] = np[0]; nv[1] = np[320]; nv[2] = np[640]; nv[3] = np[960];
                        float4 hv[2];
                        hv[0] = *(const float4*)(hb + 4 * i);
                        hv[1] = *(const float4*)(hb + BSTR + 4 * i);
                        FMA8(wv, hv);
                        #pragma unroll
                        for (int j = 0; j < 4; ++j) wv[j] = nv[j];
                        wp = np;
                    }
                    {   // tail i = 9
                        float4 hv[2];
                        hv[0] = *(const float4*)(hb + 36);
                        hv[1] = *(const float4*)(hb + BSTR + 36);
                        FMA8(wv, hv);
                    }
                }

                // fold: k-half (xor1) then mat (xor2)
                float s[4];
                #pragma unroll
                for (int j = 0; j < 4; ++j)
                    s[j] = a[j][dkh] + __shfl_xor(a[j][dkh ^ 1], 1);
                #pragma unroll
                for (int j = 0; j < 4; ++j)
                    s[j] += __shfl_xor(s[j], 2);

                const float4 bv = b4d[l * 80 + dm];
                float act0, act1;
                if (!dmat) { act0 = sigm(s[0] + bv.x);      act1 = sigm(s[1] + bv.y); }
                else       { act0 = tanh_fast(s[2] + bv.z); act1 = sigm(s[3] + bv.w); }
                const float o0 = __shfl_xor(act0, 2);
                const float o1 = __shfl_xor(act1, 2);
                if (!dmat) {
                    const float gi = act0, gf = act1, gg = o0, go = o1;
                    const int ci = l * (ENB * HID) + dkh * HID + dm;
                    const float cn = gf * cS[ci] + gi * gg;
                    cS[ci] = cn;
                    cur[l * LSTR + dkh * BSTR + dm] = go * tanh_fast(cn);
                }
            }
            __syncthreads();
        }

        const int td = t - SEQLEN;
        if (tid < ENB) {                // pred + feedback
            float s = fcb[0];
            const float* hvp = cur + 4 * LSTR + tid * BSTR;
            #pragma unroll
            for (int jj = 0; jj < HID; jj += 4) {
                const float4 wv4 = *(const float4*)&fcW[jj];
                const float4 h4  = *(const float4*)&hvp[jj];
                s += wv4.x * h4.x + wv4.y * h4.y + wv4.z * h4.z + wv4.w * h4.w;
            }
            out[(size_t)(b0 + tid) * PREDLEN + td] = s;
            sx[tid][0] = s;
        } else if (tid >= 64 && tid < 64 + ENB * 3) {
            const int qd = tid - 64;
            const int nb = qd / 3, k = qd % 3;
            sx[nb][k + 1] = ff[((size_t)(b0 + nb) * PREDLEN + td) * 3 + k];
        }
        __syncthreads();
    }
}

// ================= fallback (R5 kernel, proven) if ws too small =================
#define FQK 20
#define FCHUNK(WPTR, HPTR, I)                                                    \
    do {                                                                         \
        const float4 wA = *(const float4*)((WPTR) + 4 * (I));                    \
        const float4 wB = *(const float4*)((WPTR) + HID + 4 * (I));              \
        const float* _hb = (HPTR);                                               \
        const float4 h0 = *(const float4*)(_hb + 0 * HID + 4 * (I));             \
        const float4 h1 = *(const float4*)(_hb + 1 * HID + 4 * (I));             \
        const float4 h2 = *(const float4*)(_hb + 2 * HID + 4 * (I));             \
        const float4 h3 = *(const float4*)(_hb + 3 * HID + 4 * (I));             \
        a00 += wA.x * h0.x + wA.y * h0.y + wA.z * h0.z + wA.w * h0.w;            \
        a01 += wA.x * h1.x + wA.y * h1.y + wA.z * h1.z + wA.w * h1.w;            \
        a02 += wA.x * h2.x + wA.y * h2.y + wA.z * h2.z + wA.w * h2.w;            \
        a03 += wA.x * h3.x + wA.y * h3.y + wA.z * h3.z + wA.w * h3.w;            \
        a10 += wB.x * h0.x + wB.y * h0.y + wB.z * h0.z + wB.w * h0.w;            \
        a11 += wB.x * h1.x + wB.y * h1.y + wB.z * h1.z + wB.w * h1.w;            \
        a12 += wB.x * h2.x + wB.y * h2.y + wB.z * h2.z + wB.w * h2.w;            \
        a13 += wB.x * h3.x + wB.y * h3.y + wB.z * h3.z + wB.w * h3.w;            \
    } while (0)

__global__ __launch_bounds__(640) void lstm_fb(
    const float* __restrict__ x,    const float* __restrict__ ff,
    const float* __restrict__ eW0,  const float* __restrict__ eWih,
    const float* __restrict__ eWhh, const float* __restrict__ ebih,
    const float* __restrict__ ebhh,
    const float* __restrict__ dW0,  const float* __restrict__ dWih,
    const float* __restrict__ dWhh, const float* __restrict__ dbih,
    const float* __restrict__ dbhh,
    const float* __restrict__ fcW,  const float* __restrict__ fcb,
    float* __restrict__ out)
{
    __shared__ __align__(16) float sh[LAYERS][NB][HID];
    __shared__ __align__(16) float sc[LAYERS][NB][HID];
    __shared__ __align__(16) float sg[NB][GATES + 1];
    __shared__ __align__(16) float sx[NB][INDIM];

    const int tid = threadIdx.x;
    const int q   = tid & 3;
    const int mm  = tid >> 2;
    const int r0  = 2 * mm;
    const int b0  = blockIdx.x * NB;

    for (int i = tid; i < LAYERS * NB * HID; i += 640) {
        (&sh[0][0][0])[i] = 0.0f;
        (&sc[0][0][0])[i] = 0.0f;
    }
    const bool is_tg = (r0 >= 2 * HID) && (r0 < 3 * HID);
    const int  unb = tid / HID, uj = tid % HID;

    float bs[2][LAYERS][2];
    #pragma unroll
    for (int l = 0; l < LAYERS; ++l) {
        bs[0][l][0] = ebih[l * GATES + r0]     + ebhh[l * GATES + r0];
        bs[0][l][1] = ebih[l * GATES + r0 + 1] + ebhh[l * GATES + r0 + 1];
        bs[1][l][0] = dbih[l * GATES + r0]     + dbhh[l * GATES + r0];
        bs[1][l][1] = dbih[l * GATES + r0 + 1] + dbhh[l * GATES + r0 + 1];
    }
    const float w0e0 = eW0[r0 * INDIM + q], w0e1 = eW0[(r0 + 1) * INDIM + q];
    const float w0d0 = dW0[r0 * INDIM + q], w0d1 = dW0[(r0 + 1) * INDIM + q];

    for (int t = 0; t < TOT; ++t) {
        const bool enc = (t < SEQLEN);
        const float* Wih = enc ? eWih : dWih;
        const float* Whh = enc ? eWhh : dWhh;
        if (enc && tid < NB * INDIM) {
            const int nb = tid / INDIM, k = tid % INDIM;
            sx[nb][k] = x[((size_t)(b0 + nb) * SEQLEN + t) * INDIM + k];
        }
        __syncthreads();
        #pragma unroll
        for (int l = 0; l < LAYERS; ++l) {
            float a00 = 0.f, a01 = 0.f, a02 = 0.f, a03 = 0.f;
            float a10 = 0.f, a11 = 0.f, a12 = 0.f, a13 = 0.f;
            {
                const float* wp = Whh + ((size_t)l * GATES + r0) * HID + q * FQK;
                const float* hp = &sh[l][0][q * FQK];
                #pragma unroll
                for (int i = 0; i < FQK / 4; ++i) FCHUNK(wp, hp, i);
            }
            if (l == 0) {
                const float wa = enc ? w0e0 : w0d0;
                const float wb = enc ? w0e1 : w0d1;
                a00 += wa * sx[0][q];  a01 += wa * sx[1][q];
                a02 += wa * sx[2][q];  a03 += wa * sx[3][q];
                a10 += wb * sx[0][q];  a11 += wb * sx[1][q];
                a12 += wb * sx[2][q];  a13 += wb * sx[3][q];
            } else {
                const float* wp = Wih + ((size_t)(l - 1) * GATES + r0) * HID + q * FQK;
                const float* hp = &sh[l - 1][0][q * FQK];
                #pragma unroll
                for (int i = 0; i < FQK / 4; ++i) FCHUNK(wp, hp, i);
            }
            const float s0 = rs4(a00, a01, a02, a03, q);
            const float s1 = rs4(a10, a11, a12, a13, q);
            const float bias0 = enc ? bs[0][l][0] : bs[1][l][0];
            const float bias1 = enc ? bs[0][l][1] : bs[1][l][1];
            sg[q][r0]     = gate_act(s0 + bias0, is_tg);
            sg[q][r0 + 1] = gate_act(s1 + bias1, is_tg);
            __syncthreads();
            if (tid < NB * HID) {
                const float iv = sg[unb][uj];
                const float fv = sg[unb][uj + HID];
                const float gv = sg[unb][uj + 2 * HID];
                const float ov = sg[unb][uj + 3 * HID];
                const float cn = fv * sc[l][unb][uj] + iv * gv;
                const float hn = ov * tanh_fast(cn);
                sc[l][unb][uj] = cn;
                sh[l][unb][uj] = hn;
            }
            __syncthreads();
        }
        if (!enc) {
            const int td = t - SEQLEN;
            if (tid < NB) {
                float s = fcb[0];
                #pragma unroll
                for (int j = 0; j < HID; j += 4) {
                    const float4 wv = *(const float4*)&fcW[j];
                    const float4 hv = *(const float4*)&sh[LAYERS - 1][tid][j];
                    s += wv.x * hv.x + wv.y * hv.y + wv.z * hv.z + wv.w * hv.w;
                }
                out[(size_t)(b0 + tid) * PREDLEN + td] = s;
                sx[tid][0] = s;
            } else if (tid >= 64 && tid < 64 + NB * 3) {
                const int qd = tid - 64;
                const int nb = qd / 3, k = qd % 3;
                sx[nb][k + 1] = ff[((size_t)(b0 + nb) * PREDLEN + td) * 3 + k];
            }
        }
    }
}

extern "C" void kernel_launch(void* const* d_in, const int* in_sizes, int n_in,
                              void* d_out, int out_size, void* d_ws, size_t ws_size,
                              hipStream_t stream) {
    const float* x    = (const float*)d_in[0];
    const float* ff   = (const float*)d_in[1];
    const float* eW0  = (const float*)d_in[2];
    const float* eWih = (const float*)d_in[3];
    const float* eWhh = (const float*)d_in[4];
    const float* ebih = (const float*)d_in[5];
    const float* ebhh = (const float*)d_in[6];
    const float* dW0  = (const float*)d_in[7];
    const float* dWih = (const float*)d_in[8];
    const float* dWhh = (const float*)d_in[9];
    const float* dbih = (const float*)d_in[10];
    const float* dbhh = (const float*)d_in[11];
    const float* fcW  = (const float*)d_in[12];
    const float* fcb  = (const float*)d_in[13];

    if (ws_size >= WS_NEED) {
        prep_pack<<<(NPREP + 255) / 256, 256, 0, stream>>>(
            eW0, eWih, eWhh, ebih, ebhh, dW0, dWih, dWhh, dbih, dbhh, (float*)d_ws);
        lstm_main<<<BATCH / ENB, NTHR, 0, stream>>>(
            x, ff, fcW, fcb, (const float*)d_ws, (float*)d_out);
    } else {
        lstm_fb<<<BATCH / NB, 640, 0, stream>>>(
            x, ff, eW0, eWih, eWhh, ebih, ebhh,
            dW0, dWih, dWhh, dbih, dbhh, fcW, fcb, (float*)d_out);
    }
}

// Round 16
// 3328.226 us; speedup vs baseline: 5.6633x; 1.1139x over previous
//
#include <hip/hip_runtime.h>
#include <hip/hip_fp16.h>
#include <math.h>

// Seq2seq LSTM: 5-layer stack, HID=80, 336 enc + 48 dec steps, batch 512.
// R16: R15 (3.71ms, fp16 enc weights, absmax 2.4e-4) with the fp16->fp32
//      conversion FUSED into the FMA via the v_fma_mix_f32 pattern
//      (fmaf(__half2float(h), f, acc) — clang AMDGPU folds fpext-f16 operands
//      into mix FMAs). Removes 16 cvt + packing per chunk; math bit-identical.
//      Everything else (prep/decoder/transition/fallback) = R15 verbatim.
#define LAYERS  5
#define HID     80
#define GATES   320
#define INDIM   4
#define BATCH   512
#define SEQLEN  336
#define PREDLEN 48
#define TOT     (SEQLEN + PREDLEN)
#define NB      4            // fallback kernel's batch/block
#define ENB     2            // main kernel's batch/block
#define NTHR    800
#define NSUP    (SEQLEN + LAYERS - 1)   // 340 supersteps

#define BSTR 96
#define LSTR (ENB * BSTR)        // 192
#define HTOT (LAYERS * LSTR)     // 960 floats per parity buffer
#define CSZ  (LAYERS * ENB * HID)// 800

// ws (16B units): [enc-f16 32000][dec-f32 64000][bias_e 400][bias_d 400][w0dec 1280]
//  enc-f16: uint4[((wl*20+i)*2 + p)*160 + lt]  lt=em*2+emat, p=gate-pair
//           holds 8 halves: gates {2p,2p+1} x k-chunk i (4 halves each)
//  dec (R12): f4[((l*10+i)*4 + j)*320 + lt]    lt=dm*4+dmat*2+dkh
#define NE16    32000
#define ND4     64000
#define OFF_D   NE16             // 32000
#define OFF_BE  (NE16 + ND4)     // 96000
#define OFF_BD  (OFF_BE + 400)   // 96400
#define OFF_W0D (OFF_BD + 400)   // 96800
#define NWS4    (OFF_W0D + 1280) // 98080
#define WS_NEED ((size_t)NWS4 * 16)
#define NPREP   NWS4

__device__ __forceinline__ float sigm(float v) { return 1.0f / (1.0f + __expf(-v)); }
__device__ __forceinline__ float tanh_fast(float v) {
    return 1.0f - 2.0f / (1.0f + __expf(2.0f * v));
}
__device__ __forceinline__ float gate_act(float v, bool tg) {
    const float e = __expf(tg ? 2.0f * v : -v);
    const float r = 1.0f / (1.0f + e);
    return tg ? 1.0f - 2.0f * r : r;
}
__device__ __forceinline__ float rs4(float v0, float v1, float v2, float v3, int q) {
    float u = (q & 1) ? v1 : v0;
    float s = (q & 1) ? v0 : v1;
    u += __shfl_xor(s, 1);
    float u2 = (q & 1) ? v3 : v2;
    float s2 = (q & 1) ? v2 : v3;
    u2 += __shfl_xor(s2, 1);
    float k = (q & 2) ? u2 : u;
    float s3 = (q & 2) ? u : u2;
    k += __shfl_xor(s3, 2);
    return k;
}

__device__ __forceinline__ unsigned h2bits(__half2 h) {
    union { __half2 h; unsigned u; } c; c.h = h; return c.u;
}

// acc += f16lo(w01)*h.x + f16hi(w01)*h.y + f16lo(w23)*h.z + f16hi(w23)*h.w
// Pattern folds to v_fma_mix_f32 (op_sel lo/hi) on gfx9+; worst case cvt+fma.
__device__ __forceinline__ void fma_mix4(float& acc, unsigned w01, unsigned w23,
                                         const float4& h) {
    union { unsigned u; __half2 h2; } c01, c23;
    c01.u = w01; c23.u = w23;
    acc = fmaf(__half2float(__low2half(c01.h2)),  h.x, acc);
    acc = fmaf(__half2float(__high2half(c01.h2)), h.y, acc);
    acc = fmaf(__half2float(__low2half(c23.h2)),  h.z, acc);
    acc = fmaf(__half2float(__high2half(c23.h2)), h.w, acc);
}

// one k-chunk: 2 uint4 (16 halves = 4 gates x 4 k) against h[2] batches
#define MIXCHUNK(U0, U1, H)                                                      \
    do {                                                                         \
        fma_mix4(a[0][0], (U0).x, (U0).y, (H)[0]);                               \
        fma_mix4(a[0][1], (U0).x, (U0).y, (H)[1]);                               \
        fma_mix4(a[1][0], (U0).z, (U0).w, (H)[0]);                               \
        fma_mix4(a[1][1], (U0).z, (U0).w, (H)[1]);                               \
        fma_mix4(a[2][0], (U1).x, (U1).y, (H)[0]);                               \
        fma_mix4(a[2][1], (U1).x, (U1).y, (H)[1]);                               \
        fma_mix4(a[3][0], (U1).z, (U1).w, (H)[0]);                               \
        fma_mix4(a[3][1], (U1).z, (U1).w, (H)[1]);                               \
    } while (0)

// 8 float4-FMAs into a[4][2] (decoder, fp32)
#define FMA8(W, H)                                                               \
    do {                                                                         \
        _Pragma("unroll")                                                        \
        for (int _j = 0; _j < 4; ++_j) {                                         \
            _Pragma("unroll")                                                    \
            for (int _b = 0; _b < 2; ++_b)                                       \
                a[_j][_b] += (W)[_j].x * (H)[_b].x + (W)[_j].y * (H)[_b].y       \
                           + (W)[_j].z * (H)[_b].z + (W)[_j].w * (H)[_b].w;      \
        }                                                                        \
    } while (0)

#define LDH(SET, C)                                                              \
    do {                                                                         \
        (SET)[0] = *(const float4*)(hbase + 4 * (C));                            \
        (SET)[1] = *(const float4*)(hbase + BSTR + 4 * (C));                     \
    } while (0)

// ================= prep: pack weights/biases (R15 verbatim) =================
__global__ void prep_pack(const float* __restrict__ eW0,  const float* __restrict__ eWih,
                          const float* __restrict__ eWhh, const float* __restrict__ ebih,
                          const float* __restrict__ ebhh,
                          const float* __restrict__ dW0,  const float* __restrict__ dWih,
                          const float* __restrict__ dWhh, const float* __restrict__ dbih,
                          const float* __restrict__ dbhh, float* __restrict__ ws)
{
    const int gid = blockIdx.x * 256 + threadIdx.x;
    float4* w4 = (float4*)ws;
    if (gid < NE16) {                   // encoder fp16 layout
        const int lt = gid % 160;
        const int p  = (gid / 160) & 1;
        const int i  = (gid / 320) % 20;
        const int wl = gid / 6400;
        const int m = lt >> 1, mat = lt & 1;
        float4 f[2];
        #pragma unroll
        for (int g = 0; g < 2; ++g) {
            const int j = 2 * p + g;
            const int row = m + 80 * j;
            float4 v = make_float4(0.f, 0.f, 0.f, 0.f);
            if (wl > 0) {
                v = mat ? *(const float4*)&eWih[((size_t)(wl - 1) * GATES + row) * HID + 4 * i]
                        : *(const float4*)&eWhh[((size_t)wl * GATES + row) * HID + 4 * i];
            } else if (!mat) {
                if (i < 10) v = *(const float4*)&eWhh[(size_t)row * HID + 4 * i];
            } else {
                if (i < 10)       v = *(const float4*)&eWhh[(size_t)row * HID + 40 + 4 * i];
                else if (i == 10) v = *(const float4*)&eW0[row * INDIM];
            }
            f[g] = v;
        }
        uint4 u;
        u.x = h2bits(__floats2half2_rn(f[0].x, f[0].y));
        u.y = h2bits(__floats2half2_rn(f[0].z, f[0].w));
        u.z = h2bits(__floats2half2_rn(f[1].x, f[1].y));
        u.w = h2bits(__floats2half2_rn(f[1].z, f[1].w));
        ((uint4*)ws)[gid] = u;
        return;
    }
    int g2 = gid - NE16;
    if (g2 < ND4) {                     // decoder k-half layout (fp32, R12)
        const int lt = g2 % 320;
        const int j  = (g2 / 320) & 3;
        const int i  = (g2 / 1280) % 10;
        const int l  = g2 / 12800;
        const int dm = lt >> 2, dmat = (lt >> 1) & 1, dkh = lt & 1;
        const int row = dm + 80 * j;
        const int k0  = dkh * 40 + 4 * i;
        float4 v = make_float4(0.f, 0.f, 0.f, 0.f);
        if (l == 0) {
            if (!dmat) v = *(const float4*)&dWhh[(size_t)row * HID + k0];
        } else {
            v = dmat ? *(const float4*)&dWih[((size_t)(l - 1) * GATES + row) * HID + k0]
                     : *(const float4*)&dWhh[((size_t)l * GATES + row) * HID + k0];
        }
        w4[OFF_D + g2] = v;
        return;
    }
    int g3 = g2 - ND4;
    if (g3 < 800) {                     // biases: [ctx][l][m] f4 over gates
        const int ctx = g3 / 400, r = g3 % 400;
        const int l = r / 80, m = r % 80;
        const float* bi = ctx ? dbih : ebih;
        const float* bh = ctx ? dbhh : ebhh;
        float4 v;
        v.x = bi[l * GATES + m]       + bh[l * GATES + m];
        v.y = bi[l * GATES + m + 80]  + bh[l * GATES + m + 80];
        v.z = bi[l * GATES + m + 160] + bh[l * GATES + m + 160];
        v.w = bi[l * GATES + m + 240] + bh[l * GATES + m + 240];
        w4[OFF_BE + g3] = v;
        return;
    }
    int g4 = g3 - 800;
    if (g4 < 1280) {                    // decoder W0 rows
        const int lt = g4 % 320, j = g4 / 320;
        const int dm = lt >> 2;
        w4[OFF_W0D + g4] = *(const float4*)&dW0[(dm + 80 * j) * INDIM];
    }
}

// ================= main persistent kernel =================
__global__ __launch_bounds__(NTHR) void lstm_main(
    const float* __restrict__ x,   const float* __restrict__ ff,
    const float* __restrict__ fcW, const float* __restrict__ fcb,
    const float* __restrict__ ws,  float* __restrict__ out)
{
    __shared__ __align__(16) float hA[HTOT];     // parity-0 h (+x slots)
    __shared__ __align__(16) float hB[HTOT];     // parity-1 h
    __shared__ __align__(16) float cS[CSZ];
    __shared__ __align__(16) float sx[ENB][4];   // decoder input

    const uint4*  w16 = (const uint4*)ws;
    const float4* w4d = (const float4*)ws + OFF_D;
    const float4* b4e = (const float4*)ws + OFF_BE;
    const float4* b4d = (const float4*)ws + OFF_BD;
    const float4* w0d = (const float4*)ws + OFF_W0D;

    const int tid = threadIdx.x;
    const int b0  = blockIdx.x * ENB;

    for (int i = tid; i < HTOT; i += NTHR) { hA[i] = 0.0f; hB[i] = 0.0f; }
    for (int i = tid; i < CSZ; i += NTHR) cS[i] = 0.0f;
    if (tid < ENB)     // prestage x(0) into hB x-slots (prv of superstep 0)
        *(float4*)&hB[tid * BSTR + 80] = *(const float4*)&x[((size_t)(b0 + tid) * SEQLEN) * INDIM];
    __syncthreads();

    // ---------------- encoder: wavefront supersteps ----------------
    const int wl    = tid / 160;          // layer worker
    const int lt    = tid % 160;
    const int em    = lt >> 1;            // unit
    const int emat  = lt & 1;             // matrix half
    const int npair = (wl == 0) ? 5 : 9;  // chunk pairs; total = 2*npair+2

    #pragma unroll 1
    for (int s = 0; s < NSUP; ++s) {
        float* cur = (s & 1) ? hB : hA;
        float* prv = (s & 1) ? hA : hB;
        const int t = s - wl;

        if (tid < ENB && s + 1 < SEQLEN)  // stage x(s+1) into cur x-slot
            *(float4*)&cur[tid * BSTR + 80] =
                *(const float4*)&x[((size_t)(b0 + tid) * SEQLEN + (s + 1)) * INDIM];

        if (t >= 0 && t < SEQLEN) {
            const float* hbase = emat ? (wl ? prv + (wl - 1) * LSTR : prv + 40)
                                      : prv + wl * LSTR;
            const uint4* wq = w16 + (size_t)wl * 6400 + lt;

            // 2-deep ping-pong; fp16 weight chunks land in uint4 pairs
            uint4 uA0, uA1, uB0, uB1;
            float4 ha[2], hb[2];
            uA0 = wq[0];   uA1 = wq[160];
            uB0 = wq[320]; uB1 = wq[480];
            LDH(ha, 0);
            LDH(hb, 1);

            float a[4][2];
            #pragma unroll
            for (int j = 0; j < 4; ++j) { a[j][0] = 0.0f; a[j][1] = 0.0f; }

            #pragma unroll 1
            for (int ii = 0; ii < npair; ++ii) {   // consume 2ii,2ii+1; load +2,+3
                const int c = 2 * ii;
                MIXCHUNK(uA0, uA1, ha);
                uA0 = wq[640]; uA1 = wq[800];
                LDH(ha, c + 2);
                MIXCHUNK(uB0, uB1, hb);
                uB0 = wq[960]; uB1 = wq[1120];
                LDH(hb, c + 3);
                wq += 640;
            }
            {   // tail: chunks 2*npair, 2*npair+1
                MIXCHUNK(uA0, uA1, ha);
                MIXCHUNK(uB0, uB1, hb);
            }

            // mat fold: lane keeps batch emat
            float sA[4];
            #pragma unroll
            for (int j = 0; j < 4; ++j)
                sA[j] = a[j][emat] + __shfl_xor(a[j][emat ^ 1], 1);

            const float4 bv = b4e[wl * 80 + em];
            const float gi = sigm(sA[0] + bv.x);
            const float gf = sigm(sA[1] + bv.y);
            const float gg = tanh_fast(sA[2] + bv.z);
            const float go = sigm(sA[3] + bv.w);
            const int ci = wl * (ENB * HID) + emat * HID + em;
            const float cn = gf * cS[ci] + gi * gg;
            cS[ci] = cn;
            cur[wl * LSTR + emat * BSTR + em] = go * tanh_fast(cn);
        }
        __syncthreads();
    }

    // ---------------- transition: gather final h into hB; stage dec input ----
    for (int i = tid; i < 2 * LSTR; i += NTHR) {
        const int l = (i < LSTR) ? 1 : 3;
        const int off = i % LSTR;
        hB[l * LSTR + off] = hA[l * LSTR + off];
    }
    if (tid < ENB * INDIM)
        sx[tid >> 2][tid & 3] =
            x[((size_t)(b0 + (tid >> 2)) * SEQLEN + (SEQLEN - 1)) * INDIM + (tid & 3)];
    __syncthreads();

    // ---------------- decoder: 320 threads (R12 verbatim, fp32) ----------
    const int dm   = tid >> 2;
    const int dmat = (tid >> 1) & 1;
    const int dkh  = tid & 1;

    #pragma unroll 1
    for (int t = SEQLEN; t < TOT; ++t) {
        float* cur = (t & 1) ? hB : hA;
        float* prv = (t & 1) ? hA : hB;

        #pragma unroll 1
        for (int l = 0; l < LAYERS; ++l) {
            if (tid < 320) {
                float a[4][2];
                #pragma unroll
                for (int j = 0; j < 4; ++j) { a[j][0] = 0.0f; a[j][1] = 0.0f; }

                if (l == 0 && dmat) {
                    if (dkh == 0) {        // W0 . x (both batches)
                        const float4 xv0 = *(const float4*)&sx[0][0];
                        const float4 xv1 = *(const float4*)&sx[1][0];
                        #pragma unroll
                        for (int j = 0; j < 4; ++j) {
                            const float4 w0v = w0d[j * 320 + tid];
                            a[j][0] += w0v.x * xv0.x + w0v.y * xv0.y + w0v.z * xv0.z + w0v.w * xv0.w;
                            a[j][1] += w0v.x * xv1.x + w0v.y * xv1.y + w0v.z * xv1.z + w0v.w * xv1.w;
                        }
                    }
                } else {
                    const float* hb = (dmat ? cur + (l - 1) * LSTR : prv + l * LSTR)
                                      + dkh * 40;
                    const float4* wp = w4d + (size_t)l * 12800 + tid;
                    float4 wv[4];
                    wv[0] = wp[0]; wv[1] = wp[320]; wv[2] = wp[640]; wv[3] = wp[960];

                    #pragma unroll 1
                    for (int i = 0; i < 9; ++i) {
                        const float4* np = wp + 1280;
                        float4 nv[4];
                        nv[0] = np[0]; nv[1] = np[320]; nv[2] = np[640]; nv[3] = np[960];
                        float4 hv[2];
                        hv[0] = *(const float4*)(hb + 4 * i);
                        hv[1] = *(const float4*)(hb + BSTR + 4 * i);
                        FMA8(wv, hv);
                        #pragma unroll
                        for (int j = 0; j < 4; ++j) wv[j] = nv[j];
                        wp = np;
                    }
                    {   // tail i = 9
                        float4 hv[2];
                        hv[0] = *(const float4*)(hb + 36);
                        hv[1] = *(const float4*)(hb + BSTR + 36);
                        FMA8(wv, hv);
                    }
                }

                // fold: k-half (xor1) then mat (xor2)
                float s[4];
                #pragma unroll
                for (int j = 0; j < 4; ++j)
                    s[j] = a[j][dkh] + __shfl_xor(a[j][dkh ^ 1], 1);
                #pragma unroll
                for (int j = 0; j < 4; ++j)
                    s[j] += __shfl_xor(s[j], 2);

                const float4 bv = b4d[l * 80 + dm];
                float act0, act1;
                if (!dmat) { act0 = sigm(s[0] + bv.x);      act1 = sigm(s[1] + bv.y); }
                else       { act0 = tanh_fast(s[2] + bv.z); act1 = sigm(s[3] + bv.w); }
                const float o0 = __shfl_xor(act0, 2);
                const float o1 = __shfl_xor(act1, 2);
                if (!dmat) {
                    const float gi = act0, gf = act1, gg = o0, go = o1;
                    const int ci = l * (ENB * HID) + dkh * HID + dm;
                    const float cn = gf * cS[ci] + gi * gg;
                    cS[ci] = cn;
                    cur[l * LSTR + dkh * BSTR + dm] = go * tanh_fast(cn);
                }
            }
            __syncthreads();
        }

        const int td = t - SEQLEN;
        if (tid < ENB) {                // pred + feedback
            float s = fcb[0];
            const float* hvp = cur + 4 * LSTR + tid * BSTR;
            #pragma unroll
            for (int jj = 0; jj < HID; jj += 4) {
                const float4 wv4 = *(const float4*)&fcW[jj];
                const float4 h4  = *(const float4*)&hvp[jj];
                s += wv4.x * h4.x + wv4.y * h4.y + wv4.z * h4.z + wv4.w * h4.w;
            }
            out[(size_t)(b0 + tid) * PREDLEN + td] = s;
            sx[tid][0] = s;
        } else if (tid >= 64 && tid < 64 + ENB * 3) {
            const int qd = tid - 64;
            const int nb = qd / 3, k = qd % 3;
            sx[nb][k + 1] = ff[((size_t)(b0 + nb) * PREDLEN + td) * 3 + k];
        }
        __syncthreads();
    }
}

// ================= fallback (R5 kernel, proven) if ws too small =================
#define FQK 20
#define FCHUNK(WPTR, HPTR, I)                                                    \
    do {                                                                         \
        const float4 wA = *(const float4*)((WPTR) + 4 * (I));                    \
        const float4 wB = *(const float4*)((WPTR) + HID + 4 * (I));              \
        const float* _hb = (HPTR);                                               \
        const float4 h0 = *(const float4*)(_hb + 0 * HID + 4 * (I));             \
        const float4 h1 = *(const float4*)(_hb + 1 * HID + 4 * (I));             \
        const float4 h2 = *(const float4*)(_hb + 2 * HID + 4 * (I));             \
        const float4 h3 = *(const float4*)(_hb + 3 * HID + 4 * (I));             \
        a00 += wA.x * h0.x + wA.y * h0.y + wA.z * h0.z + wA.w * h0.w;            \
        a01 += wA.x * h1.x + wA.y * h1.y + wA.z * h1.z + wA.w * h1.w;            \
        a02 += wA.x * h2.x + wA.y * h2.y + wA.z * h2.z + wA.w * h2.w;            \
        a03 += wA.x * h3.x + wA.y * h3.y + wA.z * h3.z + wA.w * h3.w;            \
        a10 += wB.x * h0.x + wB.y * h0.y + wB.z * h0.z + wB.w * h0.w;            \
        a11 += wB.x * h1.x + wB.y * h1.y + wB.z * h1.z + wB.w * h1.w;            \
        a12 += wB.x * h2.x + wB.y * h2.y + wB.z * h2.z + wB.w * h2.w;            \
        a13 += wB.x * h3.x + wB.y * h3.y + wB.z * h3.z + wB.w * h3.w;            \
    } while (0)

__global__ __launch_bounds__(640) void lstm_fb(
    const float* __restrict__ x,    const float* __restrict__ ff,
    const float* __restrict__ eW0,  const float* __restrict__ eWih,
    const float* __restrict__ eWhh, const float* __restrict__ ebih,
    const float* __restrict__ ebhh,
    const float* __restrict__ dW0,  const float* __restrict__ dWih,
    const float* __restrict__ dWhh, const float* __restrict__ dbih,
    const float* __restrict__ dbhh,
    const float* __restrict__ fcW,  const float* __restrict__ fcb,
    float* __restrict__ out)
{
    __shared__ __align__(16) float sh[LAYERS][NB][HID];
    __shared__ __align__(16) float sc[LAYERS][NB][HID];
    __shared__ __align__(16) float sg[NB][GATES + 1];
    __shared__ __align__(16) float sx[NB][INDIM];

    const int tid = threadIdx.x;
    const int q   = tid & 3;
    const int mm  = tid >> 2;
    const int r0  = 2 * mm;
    const int b0  = blockIdx.x * NB;

    for (int i = tid; i < LAYERS * NB * HID; i += 640) {
        (&sh[0][0][0])[i] = 0.0f;
        (&sc[0][0][0])[i] = 0.0f;
    }
    const bool is_tg = (r0 >= 2 * HID) && (r0 < 3 * HID);
    const int  unb = tid / HID, uj = tid % HID;

    float bs[2][LAYERS][2];
    #pragma unroll
    for (int l = 0; l < LAYERS; ++l) {
        bs[0][l][0] = ebih[l * GATES + r0]     + ebhh[l * GATES + r0];
        bs[0][l][1] = ebih[l * GATES + r0 + 1] + ebhh[l * GATES + r0 + 1];
        bs[1][l][0] = dbih[l * GATES + r0]     + dbhh[l * GATES + r0];
        bs[1][l][1] = dbih[l * GATES + r0 + 1] + dbhh[l * GATES + r0 + 1];
    }
    const float w0e0 = eW0[r0 * INDIM + q], w0e1 = eW0[(r0 + 1) * INDIM + q];
    const float w0d0 = dW0[r0 * INDIM + q], w0d1 = dW0[(r0 + 1) * INDIM + q];

    for (int t = 0; t < TOT; ++t) {
        const bool enc = (t < SEQLEN);
        const float* Wih = enc ? eWih : dWih;
        const float* Whh = enc ? eWhh : dWhh;
        if (enc && tid < NB * INDIM) {
            const int nb = tid / INDIM, k = tid % INDIM;
            sx[nb][k] = x[((size_t)(b0 + nb) * SEQLEN + t) * INDIM + k];
        }
        __syncthreads();
        #pragma unroll
        for (int l = 0; l < LAYERS; ++l) {
            float a00 = 0.f, a01 = 0.f, a02 = 0.f, a03 = 0.f;
            float a10 = 0.f, a11 = 0.f, a12 = 0.f, a13 = 0.f;
            {
                const float* wp = Whh + ((size_t)l * GATES + r0) * HID + q * FQK;
                const float* hp = &sh[l][0][q * FQK];
                #pragma unroll
                for (int i = 0; i < FQK / 4; ++i) FCHUNK(wp, hp, i);
            }
            if (l == 0) {
                const float wa = enc ? w0e0 : w0d0;
                const float wb = enc ? w0e1 : w0d1;
                a00 += wa * sx[0][q];  a01 += wa * sx[1][q];
                a02 += wa * sx[2][q];  a03 += wa * sx[3][q];
                a10 += wb * sx[0][q];  a11 += wb * sx[1][q];
                a12 += wb * sx[2][q];  a13 += wb * sx[3][q];
            } else {
                const float* wp = Wih + ((size_t)(l - 1) * GATES + r0) * HID + q * FQK;
                const float* hp = &sh[l - 1][0][q * FQK];
                #pragma unroll
                for (int i = 0; i < FQK / 4; ++i) FCHUNK(wp, hp, i);
            }
            const float s0 = rs4(a00, a01, a02, a03, q);
            const float s1 = rs4(a10, a11, a12, a13, q);
            const float bias0 = enc ? bs[0][l][0] : bs[1][l][0];
            const float bias1 = enc ? bs[0][l][1] : bs[1][l][1];
            sg[q][r0]     = gate_act(s0 + bias0, is_tg);
            sg[q][r0 + 1] = gate_act(s1 + bias1, is_tg);
            __syncthreads();
            if (tid < NB * HID) {
                const float iv = sg[unb][uj];
                const float fv = sg[unb][uj + HID];
                const float gv = sg[unb][uj + 2 * HID];
                const float ov = sg[unb][uj + 3 * HID];
                const float cn = fv * sc[l][unb][uj] + iv * gv;
                const float hn = ov * tanh_fast(cn);
                sc[l][unb][uj] = cn;
                sh[l][unb][uj] = hn;
            }
            __syncthreads();
        }
        if (!enc) {
            const int td = t - SEQLEN;
            if (tid < NB) {
                float s = fcb[0];
                #pragma unroll
                for (int j = 0; j < HID; j += 4) {
                    const float4 wv = *(const float4*)&fcW[j];
                    const float4 hv = *(const float4*)&sh[LAYERS - 1][tid][j];
                    s += wv.x * hv.x + wv.y * hv.y + wv.z * hv.z + wv.w * hv.w;
                }
                out[(size_t)(b0 + tid) * PREDLEN + td] = s;
                sx[tid][0] = s;
            } else if (tid >= 64 && tid < 64 + NB * 3) {
                const int qd = tid - 64;
                const int nb = qd / 3, k = qd % 3;
                sx[nb][k + 1] = ff[((size_t)(b0 + nb) * PREDLEN + td) * 3 + k];
            }
        }
    }
}

extern "C" void kernel_launch(void* const* d_in, const int* in_sizes, int n_in,
                              void* d_out, int out_size, void* d_ws, size_t ws_size,
                              hipStream_t stream) {
    const float* x    = (const float*)d_in[0];
    const float* ff   = (const float*)d_in[1];
    const float* eW0  = (const float*)d_in[2];
    const float* eWih = (const float*)d_in[3];
    const float* eWhh = (const float*)d_in[4];
    const float* ebih = (const float*)d_in[5];
    const float* ebhh = (const float*)d_in[6];
    const float* dW0  = (const float*)d_in[7];
    const float* dWih = (const float*)d_in[8];
    const float* dWhh = (const float*)d_in[9];
    const float* dbih = (const float*)d_in[10];
    const float* dbhh = (const float*)d_in[11];
    const float* fcW  = (const float*)d_in[12];
    const float* fcb  = (const float*)d_in[13];

    if (ws_size >= WS_NEED) {
        prep_pack<<<(NPREP + 255) / 256, 256, 0, stream>>>(
            eW0, eWih, eWhh, ebih, ebhh, dW0, dWih, dWhh, dbih, dbhh, (float*)d_ws);
        lstm_main<<<BATCH / ENB, NTHR, 0, stream>>>(
            x, ff, fcW, fcb, (const float*)d_ws, (float*)d_out);
    } else {
        lstm_fb<<<BATCH / NB, 640, 0, stream>>>(
            x, ff, eW0, eWih, eWhh, ebih, ebhh,
            dW0, dWih, dWhh, dbih, dbhh, fcW, fcb, (float*)d_out);
    }
}

// Round 17
// 2701.683 us; speedup vs baseline: 6.9767x; 1.2319x over previous
//
#include <hip/hip_runtime.h>
#include <hip/hip_fp16.h>
#include <math.h>

// Seq2seq LSTM: 5-layer stack, HID=80, 336 enc + 48 dec steps, batch 512.
// R17: R16 (3.33ms) + encoder dot products via v_dot2_f32_f16 (2 MACs/instr,
//      fp16 pairs, fp32 accum). h gets an fp16 LDS mirror (fp32 h kept for
//      transition/decoder). Inner issue ~-40%, LDS h bytes -50%, regs fewer.
//      Decoder/prep/transition/fallback = R16 verbatim.
#define LAYERS  5
#define HID     80
#define GATES   320
#define INDIM   4
#define BATCH   512
#define SEQLEN  336
#define PREDLEN 48
#define TOT     (SEQLEN + PREDLEN)
#define NB      4            // fallback kernel's batch/block
#define ENB     2            // main kernel's batch/block
#define NTHR    800
#define NSUP    (SEQLEN + LAYERS - 1)   // 340 supersteps

#define BSTR 96
#define LSTR (ENB * BSTR)        // 192
#define HTOT (LAYERS * LSTR)     // 960 floats per parity buffer
#define CSZ  (LAYERS * ENB * HID)// 800
#define M16B 48                  // fp16 mirror: uints per batch row (96 halves)
#define M16L (ENB * M16B)        // 96 uints per layer
#define MSZ  (LAYERS * M16L)     // 480 uints per parity mirror

// ws (16B units): [enc-f16 32000][dec-f32 64000][bias_e 400][bias_d 400][w0dec 1280]
//  enc-f16: uint4[((wl*20+i)*2 + p)*160 + lt]  lt=em*2+emat, p=gate-pair
//           u.x = gate 2p k-pair(4i,4i+1), u.y = (4i+2,4i+3); u.z,u.w gate 2p+1
//  dec (R12): f4[((l*10+i)*4 + j)*320 + lt]    lt=dm*4+dmat*2+dkh
#define NE16    32000
#define ND4     64000
#define OFF_D   NE16             // 32000
#define OFF_BE  (NE16 + ND4)     // 96000
#define OFF_BD  (OFF_BE + 400)   // 96400
#define OFF_W0D (OFF_BD + 400)   // 96800
#define NWS4    (OFF_W0D + 1280) // 98080
#define WS_NEED ((size_t)NWS4 * 16)
#define NPREP   NWS4

__device__ __forceinline__ float sigm(float v) { return 1.0f / (1.0f + __expf(-v)); }
__device__ __forceinline__ float tanh_fast(float v) {
    return 1.0f - 2.0f / (1.0f + __expf(2.0f * v));
}
__device__ __forceinline__ float gate_act(float v, bool tg) {
    const float e = __expf(tg ? 2.0f * v : -v);
    const float r = 1.0f / (1.0f + e);
    return tg ? 1.0f - 2.0f * r : r;
}
__device__ __forceinline__ float rs4(float v0, float v1, float v2, float v3, int q) {
    float u = (q & 1) ? v1 : v0;
    float s = (q & 1) ? v0 : v1;
    u += __shfl_xor(s, 1);
    float u2 = (q & 1) ? v3 : v2;
    float s2 = (q & 1) ? v2 : v3;
    u2 += __shfl_xor(s2, 1);
    float k = (q & 2) ? u2 : u;
    float s3 = (q & 2) ? u : u2;
    k += __shfl_xor(s3, 2);
    return k;
}

__device__ __forceinline__ unsigned h2bits(__half2 h) {
    union { __half2 h; unsigned u; } c; c.h = h; return c.u;
}

// acc += dot2(f16x2 w, f16x2 h)  -- v_dot2_f32_f16 where available
typedef _Float16 h2v __attribute__((ext_vector_type(2)));
__device__ __forceinline__ float dot2f(unsigned wu, unsigned hu, float acc) {
    union { unsigned u; h2v v; } cw, ch;
    cw.u = wu; ch.u = hu;
#if __has_builtin(__builtin_amdgcn_fdot2)
    return __builtin_amdgcn_fdot2(cw.v, ch.v, acc, false);
#else
    acc = fmaf((float)cw.v[0], (float)ch.v[0], acc);
    return fmaf((float)cw.v[1], (float)ch.v[1], acc);
#endif
}

// one k-chunk (k=4): U0/U1 = 4 gates x 2 k-pairs; H[b] = uint2 of 2 k-pairs
#define DOT16(U0, U1, H)                                                         \
    do {                                                                         \
        a[0][0] = dot2f((U0).x, (H)[0].x, a[0][0]);                              \
        a[0][0] = dot2f((U0).y, (H)[0].y, a[0][0]);                              \
        a[0][1] = dot2f((U0).x, (H)[1].x, a[0][1]);                              \
        a[0][1] = dot2f((U0).y, (H)[1].y, a[0][1]);                              \
        a[1][0] = dot2f((U0).z, (H)[0].x, a[1][0]);                              \
        a[1][0] = dot2f((U0).w, (H)[0].y, a[1][0]);                              \
        a[1][1] = dot2f((U0).z, (H)[1].x, a[1][1]);                              \
        a[1][1] = dot2f((U0).w, (H)[1].y, a[1][1]);                              \
        a[2][0] = dot2f((U1).x, (H)[0].x, a[2][0]);                              \
        a[2][0] = dot2f((U1).y, (H)[0].y, a[2][0]);                              \
        a[2][1] = dot2f((U1).x, (H)[1].x, a[2][1]);                              \
        a[2][1] = dot2f((U1).y, (H)[1].y, a[2][1]);                              \
        a[3][0] = dot2f((U1).z, (H)[0].x, a[3][0]);                              \
        a[3][0] = dot2f((U1).w, (H)[0].y, a[3][0]);                              \
        a[3][1] = dot2f((U1).z, (H)[1].x, a[3][1]);                              \
        a[3][1] = dot2f((U1).w, (H)[1].y, a[3][1]);                              \
    } while (0)

// 8 float4-FMAs into a[4][2] (decoder, fp32)
#define FMA8(W, H)                                                               \
    do {                                                                         \
        _Pragma("unroll")                                                        \
        for (int _j = 0; _j < 4; ++_j) {                                         \
            _Pragma("unroll")                                                    \
            for (int _b = 0; _b < 2; ++_b)                                       \
                a[_j][_b] += (W)[_j].x * (H)[_b].x + (W)[_j].y * (H)[_b].y       \
                           + (W)[_j].z * (H)[_b].z + (W)[_j].w * (H)[_b].w;      \
        }                                                                        \
    } while (0)

// fp16 h pair-load: chunk C (k=4C..4C+3) for both batches from mirror base mb
#define LDH16(SET, C)                                                            \
    do {                                                                         \
        (SET)[0] = *(const uint2*)(mb + 2 * (C));                                \
        (SET)[1] = *(const uint2*)(mb + M16B + 2 * (C));                         \
    } while (0)

// ================= prep: pack weights/biases (R16 verbatim) =================
__global__ void prep_pack(const float* __restrict__ eW0,  const float* __restrict__ eWih,
                          const float* __restrict__ eWhh, const float* __restrict__ ebih,
                          const float* __restrict__ ebhh,
                          const float* __restrict__ dW0,  const float* __restrict__ dWih,
                          const float* __restrict__ dWhh, const float* __restrict__ dbih,
                          const float* __restrict__ dbhh, float* __restrict__ ws)
{
    const int gid = blockIdx.x * 256 + threadIdx.x;
    float4* w4 = (float4*)ws;
    if (gid < NE16) {                   // encoder fp16 layout
        const int lt = gid % 160;
        const int p  = (gid / 160) & 1;
        const int i  = (gid / 320) % 20;
        const int wl = gid / 6400;
        const int m = lt >> 1, mat = lt & 1;
        float4 f[2];
        #pragma unroll
        for (int g = 0; g < 2; ++g) {
            const int j = 2 * p + g;
            const int row = m + 80 * j;
            float4 v = make_float4(0.f, 0.f, 0.f, 0.f);
            if (wl > 0) {
                v = mat ? *(const float4*)&eWih[((size_t)(wl - 1) * GATES + row) * HID + 4 * i]
                        : *(const float4*)&eWhh[((size_t)wl * GATES + row) * HID + 4 * i];
            } else if (!mat) {
                if (i < 10) v = *(const float4*)&eWhh[(size_t)row * HID + 4 * i];
            } else {
                if (i < 10)       v = *(const float4*)&eWhh[(size_t)row * HID + 40 + 4 * i];
                else if (i == 10) v = *(const float4*)&eW0[row * INDIM];
            }
            f[g] = v;
        }
        uint4 u;
        u.x = h2bits(__floats2half2_rn(f[0].x, f[0].y));
        u.y = h2bits(__floats2half2_rn(f[0].z, f[0].w));
        u.z = h2bits(__floats2half2_rn(f[1].x, f[1].y));
        u.w = h2bits(__floats2half2_rn(f[1].z, f[1].w));
        ((uint4*)ws)[gid] = u;
        return;
    }
    int g2 = gid - NE16;
    if (g2 < ND4) {                     // decoder k-half layout (fp32, R12)
        const int lt = g2 % 320;
        const int j  = (g2 / 320) & 3;
        const int i  = (g2 / 1280) % 10;
        const int l  = g2 / 12800;
        const int dm = lt >> 2, dmat = (lt >> 1) & 1, dkh = lt & 1;
        const int row = dm + 80 * j;
        const int k0  = dkh * 40 + 4 * i;
        float4 v = make_float4(0.f, 0.f, 0.f, 0.f);
        if (l == 0) {
            if (!dmat) v = *(const float4*)&dWhh[(size_t)row * HID + k0];
        } else {
            v = dmat ? *(const float4*)&dWih[((size_t)(l - 1) * GATES + row) * HID + k0]
                     : *(const float4*)&dWhh[((size_t)l * GATES + row) * HID + k0];
        }
        w4[OFF_D + g2] = v;
        return;
    }
    int g3 = g2 - ND4;
    if (g3 < 800) {                     // biases: [ctx][l][m] f4 over gates
        const int ctx = g3 / 400, r = g3 % 400;
        const int l = r / 80, m = r % 80;
        const float* bi = ctx ? dbih : ebih;
        const float* bh = ctx ? dbhh : ebhh;
        float4 v;
        v.x = bi[l * GATES + m]       + bh[l * GATES + m];
        v.y = bi[l * GATES + m + 80]  + bh[l * GATES + m + 80];
        v.z = bi[l * GATES + m + 160] + bh[l * GATES + m + 160];
        v.w = bi[l * GATES + m + 240] + bh[l * GATES + m + 240];
        w4[OFF_BE + g3] = v;
        return;
    }
    int g4 = g3 - 800;
    if (g4 < 1280) {                    // decoder W0 rows
        const int lt = g4 % 320, j = g4 / 320;
        const int dm = lt >> 2;
        w4[OFF_W0D + g4] = *(const float4*)&dW0[(dm + 80 * j) * INDIM];
    }
}

// ================= main persistent kernel =================
__global__ __launch_bounds__(NTHR) void lstm_main(
    const float* __restrict__ x,   const float* __restrict__ ff,
    const float* __restrict__ fcW, const float* __restrict__ fcb,
    const float* __restrict__ ws,  float* __restrict__ out)
{
    __shared__ __align__(16) float hA[HTOT];       // parity-0 h (fp32, for dec)
    __shared__ __align__(16) float hB[HTOT];       // parity-1 h
    __shared__ __align__(16) unsigned mA16[MSZ];   // parity-0 fp16 h mirror (+x)
    __shared__ __align__(16) unsigned mB16[MSZ];   // parity-1 fp16 h mirror
    __shared__ __align__(16) float cS[CSZ];
    __shared__ __align__(16) float sx[ENB][4];     // decoder input (fp32)

    const uint4*  w16 = (const uint4*)ws;
    const float4* w4d = (const float4*)ws + OFF_D;
    const float4* b4e = (const float4*)ws + OFF_BE;
    const float4* b4d = (const float4*)ws + OFF_BD;
    const float4* w0d = (const float4*)ws + OFF_W0D;

    const int tid = threadIdx.x;
    const int b0  = blockIdx.x * ENB;

    for (int i = tid; i < HTOT; i += NTHR) { hA[i] = 0.0f; hB[i] = 0.0f; }
    for (int i = tid; i < MSZ;  i += NTHR) { mA16[i] = 0u; mB16[i] = 0u; }
    for (int i = tid; i < CSZ;  i += NTHR) cS[i] = 0.0f;
    if (tid < ENB) {   // prestage x(0) into mB16 x-halves (prv of superstep 0)
        const float4 xv = *(const float4*)&x[((size_t)(b0 + tid) * SEQLEN) * INDIM];
        __half* mx = (__half*)mB16 + (size_t)tid * 96 + 80;
        mx[0] = __float2half(xv.x); mx[1] = __float2half(xv.y);
        mx[2] = __float2half(xv.z); mx[3] = __float2half(xv.w);
    }
    __syncthreads();

    // ---------------- encoder: wavefront supersteps ----------------
    const int wl    = tid / 160;          // layer worker
    const int lt    = tid % 160;
    const int em    = lt >> 1;            // unit
    const int emat  = lt & 1;             // matrix half
    const int npair = (wl == 0) ? 5 : 9;  // chunk pairs; total = 2*npair+2

    #pragma unroll 1
    for (int s = 0; s < NSUP; ++s) {
        float*    cur  = (s & 1) ? hB : hA;
        unsigned* mcur = (s & 1) ? mB16 : mA16;
        unsigned* mprv = (s & 1) ? mA16 : mB16;
        const int t = s - wl;

        if (tid < ENB && s + 1 < SEQLEN) {  // stage x(s+1) into mcur x-halves
            const float4 xv = *(const float4*)&x[((size_t)(b0 + tid) * SEQLEN + (s + 1)) * INDIM];
            __half* mx = (__half*)mcur + (size_t)tid * 96 + 80;
            mx[0] = __float2half(xv.x); mx[1] = __float2half(xv.y);
            mx[2] = __float2half(xv.z); mx[3] = __float2half(xv.w);
        }

        if (t >= 0 && t < SEQLEN) {
            const unsigned* mb = emat ? (wl ? mprv + (wl - 1) * M16L : mprv + 20)
                                      : mprv + wl * M16L;
            const uint4* wq = w16 + (size_t)wl * 6400 + lt;

            // 2-deep ping-pong; fp16 weights (uint4 pairs) + fp16 h (uint2 pairs)
            uint4 uA0, uA1, uB0, uB1;
            uint2 ha16[2], hb16[2];
            uA0 = wq[0];   uA1 = wq[160];
            uB0 = wq[320]; uB1 = wq[480];
            LDH16(ha16, 0);
            LDH16(hb16, 1);

            float a[4][2];
            #pragma unroll
            for (int j = 0; j < 4; ++j) { a[j][0] = 0.0f; a[j][1] = 0.0f; }

            #pragma unroll 1
            for (int ii = 0; ii < npair; ++ii) {   // consume 2ii,2ii+1; load +2,+3
                const int c = 2 * ii;
                DOT16(uA0, uA1, ha16);
                uA0 = wq[640]; uA1 = wq[800];
                LDH16(ha16, c + 2);
                DOT16(uB0, uB1, hb16);
                uB0 = wq[960]; uB1 = wq[1120];
                LDH16(hb16, c + 3);
                wq += 640;
            }
            {   // tail: chunks 2*npair, 2*npair+1
                DOT16(uA0, uA1, ha16);
                DOT16(uB0, uB1, hb16);
            }

            // mat fold: lane keeps batch emat
            float sA[4];
            #pragma unroll
            for (int j = 0; j < 4; ++j)
                sA[j] = a[j][emat] + __shfl_xor(a[j][emat ^ 1], 1);

            const float4 bv = b4e[wl * 80 + em];
            const float gi = sigm(sA[0] + bv.x);
            const float gf = sigm(sA[1] + bv.y);
            const float gg = tanh_fast(sA[2] + bv.z);
            const float go = sigm(sA[3] + bv.w);
            const int ci = wl * (ENB * HID) + emat * HID + em;
            const float cn = gf * cS[ci] + gi * gg;
            cS[ci] = cn;
            const float hn = go * tanh_fast(cn);
            cur[wl * LSTR + emat * BSTR + em] = hn;                       // fp32 (dec)
            ((__half*)mcur)[(size_t)(wl * 2 + emat) * 96 + em] = __float2half(hn);
        }
        __syncthreads();
    }

    // ---------------- transition: gather final h into hB; stage dec input ----
    for (int i = tid; i < 2 * LSTR; i += NTHR) {
        const int l = (i < LSTR) ? 1 : 3;
        const int off = i % LSTR;
        hB[l * LSTR + off] = hA[l * LSTR + off];
    }
    if (tid < ENB * INDIM)
        sx[tid >> 2][tid & 3] =
            x[((size_t)(b0 + (tid >> 2)) * SEQLEN + (SEQLEN - 1)) * INDIM + (tid & 3)];
    __syncthreads();

    // ---------------- decoder: 320 threads (R12 verbatim, fp32) ----------
    const int dm   = tid >> 2;
    const int dmat = (tid >> 1) & 1;
    const int dkh  = tid & 1;

    #pragma unroll 1
    for (int t = SEQLEN; t < TOT; ++t) {
        float* cur = (t & 1) ? hB : hA;
        float* prv = (t & 1) ? hA : hB;

        #pragma unroll 1
        for (int l = 0; l < LAYERS; ++l) {
            if (tid < 320) {
                float a[4][2];
                #pragma unroll
                for (int j = 0; j < 4; ++j) { a[j][0] = 0.0f; a[j][1] = 0.0f; }

                if (l == 0 && dmat) {
                    if (dkh == 0) {        // W0 . x (both batches)
                        const float4 xv0 = *(const float4*)&sx[0][0];
                        const float4 xv1 = *(const float4*)&sx[1][0];
                        #pragma unroll
                        for (int j = 0; j < 4; ++j) {
                            const float4 w0v = w0d[j * 320 + tid];
                            a[j][0] += w0v.x * xv0.x + w0v.y * xv0.y + w0v.z * xv0.z + w0v.w * xv0.w;
                            a[j][1] += w0v.x * xv1.x + w0v.y * xv1.y + w0v.z * xv1.z + w0v.w * xv1.w;
                        }
                    }
                } else {
                    const float* hb = (dmat ? cur + (l - 1) * LSTR : prv + l * LSTR)
                                      + dkh * 40;
                    const float4* wp = w4d + (size_t)l * 12800 + tid;
                    float4 wv[4];
                    wv[0] = wp[0]; wv[1] = wp[320]; wv[2] = wp[640]; wv[3] = wp[960];

                    #pragma unroll 1
                    for (int i = 0; i < 9; ++i) {
                        const float4* np = wp + 1280;
                        float4 nv[4];
                        nv[0] = np[0]; nv[1] = np[320]; nv[2] = np[640]; nv[3] = np[960];
                        float4 hv[2];
                        hv[0] = *(const float4*)(hb + 4 * i);
                        hv[1] = *(const float4*)(hb + BSTR + 4 * i);
                        FMA8(wv, hv);
                        #pragma unroll
                        for (int j = 0; j < 4; ++j) wv[j] = nv[j];
                        wp = np;
                    }
                    {   // tail i = 9
                        float4 hv[2];
                        hv[0] = *(const float4*)(hb + 36);
                        hv[1] = *(const float4*)(hb + BSTR + 36);
                        FMA8(wv, hv);
                    }
                }

                // fold: k-half (xor1) then mat (xor2)
                float s[4];
                #pragma unroll
                for (int j = 0; j < 4; ++j)
                    s[j] = a[j][dkh] + __shfl_xor(a[j][dkh ^ 1], 1);
                #pragma unroll
                for (int j = 0; j < 4; ++j)
                    s[j] += __shfl_xor(s[j], 2);

                const float4 bv = b4d[l * 80 + dm];
                float act0, act1;
                if (!dmat) { act0 = sigm(s[0] + bv.x);      act1 = sigm(s[1] + bv.y); }
                else       { act0 = tanh_fast(s[2] + bv.z); act1 = sigm(s[3] + bv.w); }
                const float o0 = __shfl_xor(act0, 2);
                const float o1 = __shfl_xor(act1, 2);
                if (!dmat) {
                    const float gi = act0, gf = act1, gg = o0, go = o1;
                    const int ci = l * (ENB * HID) + dkh * HID + dm;
                    const float cn = gf * cS[ci] + gi * gg;
                    cS[ci] = cn;
                    cur[l * LSTR + dkh * BSTR + dm] = go * tanh_fast(cn);
                }
            }
            __syncthreads();
        }

        const int td = t - SEQLEN;
        if (tid < ENB) {                // pred + feedback
            float s = fcb[0];
            const float* hvp = cur + 4 * LSTR + tid * BSTR;
            #pragma unroll
            for (int jj = 0; jj < HID; jj += 4) {
                const float4 wv4 = *(const float4*)&fcW[jj];
                const float4 h4  = *(const float4*)&hvp[jj];
                s += wv4.x * h4.x + wv4.y * h4.y + wv4.z * h4.z + wv4.w * h4.w;
            }
            out[(size_t)(b0 + tid) * PREDLEN + td] = s;
            sx[tid][0] = s;
        } else if (tid >= 64 && tid < 64 + ENB * 3) {
            const int qd = tid - 64;
            const int nb = qd / 3, k = qd % 3;
            sx[nb][k + 1] = ff[((size_t)(b0 + nb) * PREDLEN + td) * 3 + k];
        }
        __syncthreads();
    }
}

// ================= fallback (R5 kernel, proven) if ws too small =================
#define FQK 20
#define FCHUNK(WPTR, HPTR, I)                                                    \
    do {                                                                         \
        const float4 wA = *(const float4*)((WPTR) + 4 * (I));                    \
        const float4 wB = *(const float4*)((WPTR) + HID + 4 * (I));              \
        const float* _hb = (HPTR);                                               \
        const float4 h0 = *(const float4*)(_hb + 0 * HID + 4 * (I));             \
        const float4 h1 = *(const float4*)(_hb + 1 * HID + 4 * (I));             \
        const float4 h2 = *(const float4*)(_hb + 2 * HID + 4 * (I));             \
        const float4 h3 = *(const float4*)(_hb + 3 * HID + 4 * (I));             \
        a00 += wA.x * h0.x + wA.y * h0.y + wA.z * h0.z + wA.w * h0.w;            \
        a01 += wA.x * h1.x + wA.y * h1.y + wA.z * h1.z + wA.w * h1.w;            \
        a02 += wA.x * h2.x + wA.y * h2.y + wA.z * h2.z + wA.w * h2.w;            \
        a03 += wA.x * h3.x + wA.y * h3.y + wA.z * h3.z + wA.w * h3.w;            \
        a10 += wB.x * h0.x + wB.y * h0.y + wB.z * h0.z + wB.w * h0.w;            \
        a11 += wB.x * h1.x + wB.y * h1.y + wB.z * h1.z + wB.w * h1.w;            \
        a12 += wB.x * h2.x + wB.y * h2.y + wB.z * h2.z + wB.w * h2.w;            \
        a13 += wB.x * h3.x + wB.y * h3.y + wB.z * h3.z + wB.w * h3.w;            \
    } while (0)

__global__ __launch_bounds__(640) void lstm_fb(
    const float* __restrict__ x,    const float* __restrict__ ff,
    const float* __restrict__ eW0,  const float* __restrict__ eWih,
    const float* __restrict__ eWhh, const float* __restrict__ ebih,
    const float* __restrict__ ebhh,
    const float* __restrict__ dW0,  const float* __restrict__ dWih,
    const float* __restrict__ dWhh, const float* __restrict__ dbih,
    const float* __restrict__ dbhh,
    const float* __restrict__ fcW,  const float* __restrict__ fcb,
    float* __restrict__ out)
{
    __shared__ __align__(16) float sh[LAYERS][NB][HID];
    __shared__ __align__(16) float sc[LAYERS][NB][HID];
    __shared__ __align__(16) float sg[NB][GATES + 1];
    __shared__ __align__(16) float sx[NB][INDIM];

    const int tid = threadIdx.x;
    const int q   = tid & 3;
    const int mm  = tid >> 2;
    const int r0  = 2 * mm;
    const int b0  = blockIdx.x * NB;

    for (int i = tid; i < LAYERS * NB * HID; i += 640) {
        (&sh[0][0][0])[i] = 0.0f;
        (&sc[0][0][0])[i] = 0.0f;
    }
    const bool is_tg = (r0 >= 2 * HID) && (r0 < 3 * HID);
    const int  unb = tid / HID, uj = tid % HID;

    float bs[2][LAYERS][2];
    #pragma unroll
    for (int l = 0; l < LAYERS; ++l) {
        bs[0][l][0] = ebih[l * GATES + r0]     + ebhh[l * GATES + r0];
        bs[0][l][1] = ebih[l * GATES + r0 + 1] + ebhh[l * GATES + r0 + 1];
        bs[1][l][0] = dbih[l * GATES + r0]     + dbhh[l * GATES + r0];
        bs[1][l][1] = dbih[l * GATES + r0 + 1] + dbhh[l * GATES + r0 + 1];
    }
    const float w0e0 = eW0[r0 * INDIM + q], w0e1 = eW0[(r0 + 1) * INDIM + q];
    const float w0d0 = dW0[r0 * INDIM + q], w0d1 = dW0[(r0 + 1) * INDIM + q];

    for (int t = 0; t < TOT; ++t) {
        const bool enc = (t < SEQLEN);
        const float* Wih = enc ? eWih : dWih;
        const float* Whh = enc ? eWhh : dWhh;
        if (enc && tid < NB * INDIM) {
            const int nb = tid / INDIM, k = tid % INDIM;
            sx[nb][k] = x[((size_t)(b0 + nb) * SEQLEN + t) * INDIM + k];
        }
        __syncthreads();
        #pragma unroll
        for (int l = 0; l < LAYERS; ++l) {
            float a00 = 0.f, a01 = 0.f, a02 = 0.f, a03 = 0.f;
            float a10 = 0.f, a11 = 0.f, a12 = 0.f, a13 = 0.f;
            {
                const float* wp = Whh + ((size_t)l * GATES + r0) * HID + q * FQK;
                const float* hp = &sh[l][0][q * FQK];
                #pragma unroll
                for (int i = 0; i < FQK / 4; ++i) FCHUNK(wp, hp, i);
            }
            if (l == 0) {
                const float wa = enc ? w0e0 : w0d0;
                const float wb = enc ? w0e1 : w0d1;
                a00 += wa * sx[0][q];  a01 += wa * sx[1][q];
                a02 += wa * sx[2][q];  a03 += wa * sx[3][q];
                a10 += wb * sx[0][q];  a11 += wb * sx[1][q];
                a12 += wb * sx[2][q];  a13 += wb * sx[3][q];
            } else {
                const float* wp = Wih + ((size_t)(l - 1) * GATES + r0) * HID + q * FQK;
                const float* hp = &sh[l - 1][0][q * FQK];
                #pragma unroll
                for (int i = 0; i < FQK / 4; ++i) FCHUNK(wp, hp, i);
            }
            const float s0 = rs4(a00, a01, a02, a03, q);
            const float s1 = rs4(a10, a11, a12, a13, q);
            const float bias0 = enc ? bs[0][l][0] : bs[1][l][0];
            const float bias1 = enc ? bs[0][l][1] : bs[1][l][1];
            sg[q][r0]     = gate_act(s0 + bias0, is_tg);
            sg[q][r0 + 1] = gate_act(s1 + bias1, is_tg);
            __syncthreads();
            if (tid < NB * HID) {
                const float iv = sg[unb][uj];
                const float fv = sg[unb][uj + HID];
                const float gv = sg[unb][uj + 2 * HID];
                const float ov = sg[unb][uj + 3 * HID];
                const float cn = fv * sc[l][unb][uj] + iv * gv;
                const float hn = ov * tanh_fast(cn);
                sc[l][unb][uj] = cn;
                sh[l][unb][uj] = hn;
            }
            __syncthreads();
        }
        if (!enc) {
            const int td = t - SEQLEN;
            if (tid < NB) {
                float s = fcb[0];
                #pragma unroll
                for (int j = 0; j < HID; j += 4) {
                    const float4 wv = *(const float4*)&fcW[j];
                    const float4 hv = *(const float4*)&sh[LAYERS - 1][tid][j];
                    s += wv.x * hv.x + wv.y * hv.y + wv.z * hv.z + wv.w * hv.w;
                }
                out[(size_t)(b0 + tid) * PREDLEN + td] = s;
                sx[tid][0] = s;
            } else if (tid >= 64 && tid < 64 + NB * 3) {
                const int qd = tid - 64;
                const int nb = qd / 3, k = qd % 3;
                sx[nb][k + 1] = ff[((size_t)(b0 + nb) * PREDLEN + td) * 3 + k];
            }
        }
    }
}

extern "C" void kernel_launch(void* const* d_in, const int* in_sizes, int n_in,
                              void* d_out, int out_size, void* d_ws, size_t ws_size,
                              hipStream_t stream) {
    const float* x    = (const float*)d_in[0];
    const float* ff   = (const float*)d_in[1];
    const float* eW0  = (const float*)d_in[2];
    const float* eWih = (const float*)d_in[3];
    const float* eWhh = (const float*)d_in[4];
    const float* ebih = (const float*)d_in[5];
    const float* ebhh = (const float*)d_in[6];
    const float* dW0  = (const float*)d_in[7];
    const float* dWih = (const float*)d_in[8];
    const float* dWhh = (const float*)d_in[9];
    const float* dbih = (const float*)d_in[10];
    const float* dbhh = (const float*)d_in[11];
    const float* fcW  = (const float*)d_in[12];
    const float* fcb  = (const float*)d_in[13];

    if (ws_size >= WS_NEED) {
        prep_pack<<<(NPREP + 255) / 256, 256, 0, stream>>>(
            eW0, eWih, eWhh, ebih, ebhh, dW0, dWih, dWhh, dbih, dbhh, (float*)d_ws);
        lstm_main<<<BATCH / ENB, NTHR, 0, stream>>>(
            x, ff, fcW, fcb, (const float*)d_ws, (float*)d_out);
    } else {
        lstm_fb<<<BATCH / NB, 640, 0, stream>>>(
            x, ff, eW0, eWih, eWhh, ebih, ebhh,
            dW0, dWih, dWhh, dbih, dbhh, fcW, fcb, (float*)d_out);
    }
}

// Round 18
// 2648.504 us; speedup vs baseline: 7.1168x; 1.0201x over previous
//
#include <hip/hip_runtime.h>
#include <hip/hip_fp16.h>
#include <math.h>

// Seq2seq LSTM: 5-layer stack, HID=80, 336 enc + 48 dec steps, batch 512.
// R18: R17 (2.70ms, fp16 weights + v_dot2) with the encoder inner loop
//      deepened to a 4-DEEP named register ring (prefetch ~3 chunks ~400cy,
//      covers L2 latency; R13's fp32 ring spilled, fp16 halves the live set)
//      + __launch_bounds__(NTHR,1) so the allocator targets 1 block/CU
//      (prevents the 64-VGPR cap that caused R13's spill).
//      Decoder/prep/transition/fallback = R17 verbatim.
#define LAYERS  5
#define HID     80
#define GATES   320
#define INDIM   4
#define BATCH   512
#define SEQLEN  336
#define PREDLEN 48
#define TOT     (SEQLEN + PREDLEN)
#define NB      4            // fallback kernel's batch/block
#define ENB     2            // main kernel's batch/block
#define NTHR    800
#define NSUP    (SEQLEN + LAYERS - 1)   // 340 supersteps

#define BSTR 96
#define LSTR (ENB * BSTR)        // 192
#define HTOT (LAYERS * LSTR)     // 960 floats per parity buffer
#define CSZ  (LAYERS * ENB * HID)// 800
#define M16B 48                  // fp16 mirror: uints per batch row (96 halves)
#define M16L (ENB * M16B)        // 96 uints per layer
#define MSZ  (LAYERS * M16L)     // 480 uints per parity mirror

// ws (16B units): [enc-f16 32000][dec-f32 64000][bias_e 400][bias_d 400][w0dec 1280]
//  enc-f16: uint4[((wl*20+i)*2 + p)*160 + lt]  lt=em*2+emat, p=gate-pair
//  dec (R12): f4[((l*10+i)*4 + j)*320 + lt]    lt=dm*4+dmat*2+dkh
#define NE16    32000
#define ND4     64000
#define OFF_D   NE16             // 32000
#define OFF_BE  (NE16 + ND4)     // 96000
#define OFF_BD  (OFF_BE + 400)   // 96400
#define OFF_W0D (OFF_BD + 400)   // 96800
#define NWS4    (OFF_W0D + 1280) // 98080
#define WS_NEED ((size_t)NWS4 * 16)
#define NPREP   NWS4

__device__ __forceinline__ float sigm(float v) { return 1.0f / (1.0f + __expf(-v)); }
__device__ __forceinline__ float tanh_fast(float v) {
    return 1.0f - 2.0f / (1.0f + __expf(2.0f * v));
}
__device__ __forceinline__ float gate_act(float v, bool tg) {
    const float e = __expf(tg ? 2.0f * v : -v);
    const float r = 1.0f / (1.0f + e);
    return tg ? 1.0f - 2.0f * r : r;
}
__device__ __forceinline__ float rs4(float v0, float v1, float v2, float v3, int q) {
    float u = (q & 1) ? v1 : v0;
    float s = (q & 1) ? v0 : v1;
    u += __shfl_xor(s, 1);
    float u2 = (q & 1) ? v3 : v2;
    float s2 = (q & 1) ? v2 : v3;
    u2 += __shfl_xor(s2, 1);
    float k = (q & 2) ? u2 : u;
    float s3 = (q & 2) ? u : u2;
    k += __shfl_xor(s3, 2);
    return k;
}

__device__ __forceinline__ unsigned h2bits(__half2 h) {
    union { __half2 h; unsigned u; } c; c.h = h; return c.u;
}

// acc += dot2(f16x2 w, f16x2 h)  -- v_dot2_f32_f16 where available
typedef _Float16 h2v __attribute__((ext_vector_type(2)));
__device__ __forceinline__ float dot2f(unsigned wu, unsigned hu, float acc) {
    union { unsigned u; h2v v; } cw, ch;
    cw.u = wu; ch.u = hu;
#if __has_builtin(__builtin_amdgcn_fdot2)
    return __builtin_amdgcn_fdot2(cw.v, ch.v, acc, false);
#else
    acc = fmaf((float)cw.v[0], (float)ch.v[0], acc);
    return fmaf((float)cw.v[1], (float)ch.v[1], acc);
#endif
}

// one k-chunk (k=4): U0/U1 = 4 gates x 2 k-pairs; H[b] = uint2 of 2 k-pairs
#define DOT16(U0, U1, H)                                                         \
    do {                                                                         \
        a[0][0] = dot2f((U0).x, (H)[0].x, a[0][0]);                              \
        a[0][0] = dot2f((U0).y, (H)[0].y, a[0][0]);                              \
        a[0][1] = dot2f((U0).x, (H)[1].x, a[0][1]);                              \
        a[0][1] = dot2f((U0).y, (H)[1].y, a[0][1]);                              \
        a[1][0] = dot2f((U0).z, (H)[0].x, a[1][0]);                              \
        a[1][0] = dot2f((U0).w, (H)[0].y, a[1][0]);                              \
        a[1][1] = dot2f((U0).z, (H)[1].x, a[1][1]);                              \
        a[1][1] = dot2f((U0).w, (H)[1].y, a[1][1]);                              \
        a[2][0] = dot2f((U1).x, (H)[0].x, a[2][0]);                              \
        a[2][0] = dot2f((U1).y, (H)[0].y, a[2][0]);                              \
        a[2][1] = dot2f((U1).x, (H)[1].x, a[2][1]);                              \
        a[2][1] = dot2f((U1).y, (H)[1].y, a[2][1]);                              \
        a[3][0] = dot2f((U1).z, (H)[0].x, a[3][0]);                              \
        a[3][0] = dot2f((U1).w, (H)[0].y, a[3][0]);                              \
        a[3][1] = dot2f((U1).z, (H)[1].x, a[3][1]);                              \
        a[3][1] = dot2f((U1).w, (H)[1].y, a[3][1]);                              \
    } while (0)

// 8 float4-FMAs into a[4][2] (decoder, fp32)
#define FMA8(W, H)                                                               \
    do {                                                                         \
        _Pragma("unroll")                                                        \
        for (int _j = 0; _j < 4; ++_j) {                                         \
            _Pragma("unroll")                                                    \
            for (int _b = 0; _b < 2; ++_b)                                       \
                a[_j][_b] += (W)[_j].x * (H)[_b].x + (W)[_j].y * (H)[_b].y       \
                           + (W)[_j].z * (H)[_b].z + (W)[_j].w * (H)[_b].w;      \
        }                                                                        \
    } while (0)

// fp16 h pair-load: chunk C (k=4C..4C+3) for both batches from mirror base mb
#define LDH16(SET, C)                                                            \
    do {                                                                         \
        (SET)[0] = *(const uint2*)(mb + 2 * (C));                                \
        (SET)[1] = *(const uint2*)(mb + M16B + 2 * (C));                         \
    } while (0)

// ================= prep: pack weights/biases (R17 verbatim) =================
__global__ void prep_pack(const float* __restrict__ eW0,  const float* __restrict__ eWih,
                          const float* __restrict__ eWhh, const float* __restrict__ ebih,
                          const float* __restrict__ ebhh,
                          const float* __restrict__ dW0,  const float* __restrict__ dWih,
                          const float* __restrict__ dWhh, const float* __restrict__ dbih,
                          const float* __restrict__ dbhh, float* __restrict__ ws)
{
    const int gid = blockIdx.x * 256 + threadIdx.x;
    float4* w4 = (float4*)ws;
    if (gid < NE16) {                   // encoder fp16 layout
        const int lt = gid % 160;
        const int p  = (gid / 160) & 1;
        const int i  = (gid / 320) % 20;
        const int wl = gid / 6400;
        const int m = lt >> 1, mat = lt & 1;
        float4 f[2];
        #pragma unroll
        for (int g = 0; g < 2; ++g) {
            const int j = 2 * p + g;
            const int row = m + 80 * j;
            float4 v = make_float4(0.f, 0.f, 0.f, 0.f);
            if (wl > 0) {
                v = mat ? *(const float4*)&eWih[((size_t)(wl - 1) * GATES + row) * HID + 4 * i]
                        : *(const float4*)&eWhh[((size_t)wl * GATES + row) * HID + 4 * i];
            } else if (!mat) {
                if (i < 10) v = *(const float4*)&eWhh[(size_t)row * HID + 4 * i];
            } else {
                if (i < 10)       v = *(const float4*)&eWhh[(size_t)row * HID + 40 + 4 * i];
                else if (i == 10) v = *(const float4*)&eW0[row * INDIM];
            }
            f[g] = v;
        }
        uint4 u;
        u.x = h2bits(__floats2half2_rn(f[0].x, f[0].y));
        u.y = h2bits(__floats2half2_rn(f[0].z, f[0].w));
        u.z = h2bits(__floats2half2_rn(f[1].x, f[1].y));
        u.w = h2bits(__floats2half2_rn(f[1].z, f[1].w));
        ((uint4*)ws)[gid] = u;
        return;
    }
    int g2 = gid - NE16;
    if (g2 < ND4) {                     // decoder k-half layout (fp32, R12)
        const int lt = g2 % 320;
        const int j  = (g2 / 320) & 3;
        const int i  = (g2 / 1280) % 10;
        const int l  = g2 / 12800;
        const int dm = lt >> 2, dmat = (lt >> 1) & 1, dkh = lt & 1;
        const int row = dm + 80 * j;
        const int k0  = dkh * 40 + 4 * i;
        float4 v = make_float4(0.f, 0.f, 0.f, 0.f);
        if (l == 0) {
            if (!dmat) v = *(const float4*)&dWhh[(size_t)row * HID + k0];
        } else {
            v = dmat ? *(const float4*)&dWih[((size_t)(l - 1) * GATES + row) * HID + k0]
                     : *(const float4*)&dWhh[((size_t)l * GATES + row) * HID + k0];
        }
        w4[OFF_D + g2] = v;
        return;
    }
    int g3 = g2 - ND4;
    if (g3 < 800) {                     // biases: [ctx][l][m] f4 over gates
        const int ctx = g3 / 400, r = g3 % 400;
        const int l = r / 80, m = r % 80;
        const float* bi = ctx ? dbih : ebih;
        const float* bh = ctx ? dbhh : ebhh;
        float4 v;
        v.x = bi[l * GATES + m]       + bh[l * GATES + m];
        v.y = bi[l * GATES + m + 80]  + bh[l * GATES + m + 80];
        v.z = bi[l * GATES + m + 160] + bh[l * GATES + m + 160];
        v.w = bi[l * GATES + m + 240] + bh[l * GATES + m + 240];
        w4[OFF_BE + g3] = v;
        return;
    }
    int g4 = g3 - 800;
    if (g4 < 1280) {                    // decoder W0 rows
        const int lt = g4 % 320, j = g4 / 320;
        const int dm = lt >> 2;
        w4[OFF_W0D + g4] = *(const float4*)&dW0[(dm + 80 * j) * INDIM];
    }
}

// ================= main persistent kernel =================
__global__ __launch_bounds__(NTHR, 1) void lstm_main(
    const float* __restrict__ x,   const float* __restrict__ ff,
    const float* __restrict__ fcW, const float* __restrict__ fcb,
    const float* __restrict__ ws,  float* __restrict__ out)
{
    __shared__ __align__(16) float hA[HTOT];       // parity-0 h (fp32, for dec)
    __shared__ __align__(16) float hB[HTOT];       // parity-1 h
    __shared__ __align__(16) unsigned mA16[MSZ];   // parity-0 fp16 h mirror (+x)
    __shared__ __align__(16) unsigned mB16[MSZ];   // parity-1 fp16 h mirror
    __shared__ __align__(16) float cS[CSZ];
    __shared__ __align__(16) float sx[ENB][4];     // decoder input (fp32)

    const uint4*  w16 = (const uint4*)ws;
    const float4* w4d = (const float4*)ws + OFF_D;
    const float4* b4e = (const float4*)ws + OFF_BE;
    const float4* b4d = (const float4*)ws + OFF_BD;
    const float4* w0d = (const float4*)ws + OFF_W0D;

    const int tid = threadIdx.x;
    const int b0  = blockIdx.x * ENB;

    for (int i = tid; i < HTOT; i += NTHR) { hA[i] = 0.0f; hB[i] = 0.0f; }
    for (int i = tid; i < MSZ;  i += NTHR) { mA16[i] = 0u; mB16[i] = 0u; }
    for (int i = tid; i < CSZ;  i += NTHR) cS[i] = 0.0f;
    if (tid < ENB) {   // prestage x(0) into mB16 x-halves (prv of superstep 0)
        const float4 xv = *(const float4*)&x[((size_t)(b0 + tid) * SEQLEN) * INDIM];
        __half* mx = (__half*)mB16 + (size_t)tid * 96 + 80;
        mx[0] = __float2half(xv.x); mx[1] = __float2half(xv.y);
        mx[2] = __float2half(xv.z); mx[3] = __float2half(xv.w);
    }
    __syncthreads();

    // ---------------- encoder: wavefront supersteps ----------------
    const int wl    = tid / 160;          // layer worker
    const int lt    = tid % 160;
    const int em    = lt >> 1;            // unit
    const int emat  = lt & 1;             // matrix half
    const int nquad = (wl == 0) ? 3 : 5;  // 4-chunk groups; chunks = 4*nquad

    #pragma unroll 1
    for (int s = 0; s < NSUP; ++s) {
        float*    cur  = (s & 1) ? hB : hA;
        unsigned* mcur = (s & 1) ? mB16 : mA16;
        unsigned* mprv = (s & 1) ? mA16 : mB16;
        const int t = s - wl;

        if (tid < ENB && s + 1 < SEQLEN) {  // stage x(s+1) into mcur x-halves
            const float4 xv = *(const float4*)&x[((size_t)(b0 + tid) * SEQLEN + (s + 1)) * INDIM];
            __half* mx = (__half*)mcur + (size_t)tid * 96 + 80;
            mx[0] = __float2half(xv.x); mx[1] = __float2half(xv.y);
            mx[2] = __float2half(xv.z); mx[3] = __float2half(xv.w);
        }

        if (t >= 0 && t < SEQLEN) {
            const unsigned* mb = emat ? (wl ? mprv + (wl - 1) * M16L : mprv + 20)
                                      : mprv + wl * M16L;
            const uint4* wq = w16 + (size_t)wl * 6400 + lt;

            // 4-deep named ring: w chunks 0..3 + h chunks 0..3 in flight
            uint4 u0a = wq[0],   u0b = wq[160];
            uint4 u1a = wq[320], u1b = wq[480];
            uint4 u2a = wq[640], u2b = wq[800];
            uint4 u3a = wq[960], u3b = wq[1120];
            uint2 h0[2], h1[2], h2[2], h3[2];
            LDH16(h0, 0); LDH16(h1, 1); LDH16(h2, 2); LDH16(h3, 3);

            float a[4][2];
            #pragma unroll
            for (int j = 0; j < 4; ++j) { a[j][0] = 0.0f; a[j][1] = 0.0f; }

            #pragma unroll 1
            for (int q4 = 0; q4 < nquad - 1; ++q4) {   // consume quad, load next
                const int c = 4 * q4;
                DOT16(u0a, u0b, h0); u0a = wq[1280]; u0b = wq[1440]; LDH16(h0, c + 4);
                DOT16(u1a, u1b, h1); u1a = wq[1600]; u1b = wq[1760]; LDH16(h1, c + 5);
                DOT16(u2a, u2b, h2); u2a = wq[1920]; u2b = wq[2080]; LDH16(h2, c + 6);
                DOT16(u3a, u3b, h3); u3a = wq[2240]; u3b = wq[2400]; LDH16(h3, c + 7);
                wq += 1280;
            }
            // final quad: no loads
            DOT16(u0a, u0b, h0);
            DOT16(u1a, u1b, h1);
            DOT16(u2a, u2b, h2);
            DOT16(u3a, u3b, h3);

            // mat fold: lane keeps batch emat
            float sA[4];
            #pragma unroll
            for (int j = 0; j < 4; ++j)
                sA[j] = a[j][emat] + __shfl_xor(a[j][emat ^ 1], 1);

            const float4 bv = b4e[wl * 80 + em];
            const float gi = sigm(sA[0] + bv.x);
            const float gf = sigm(sA[1] + bv.y);
            const float gg = tanh_fast(sA[2] + bv.z);
            const float go = sigm(sA[3] + bv.w);
            const int ci = wl * (ENB * HID) + emat * HID + em;
            const float cn = gf * cS[ci] + gi * gg;
            cS[ci] = cn;
            const float hn = go * tanh_fast(cn);
            cur[wl * LSTR + emat * BSTR + em] = hn;                       // fp32 (dec)
            ((__half*)mcur)[(size_t)(wl * 2 + emat) * 96 + em] = __float2half(hn);
        }
        __syncthreads();
    }

    // ---------------- transition: gather final h into hB; stage dec input ----
    for (int i = tid; i < 2 * LSTR; i += NTHR) {
        const int l = (i < LSTR) ? 1 : 3;
        const int off = i % LSTR;
        hB[l * LSTR + off] = hA[l * LSTR + off];
    }
    if (tid < ENB * INDIM)
        sx[tid >> 2][tid & 3] =
            x[((size_t)(b0 + (tid >> 2)) * SEQLEN + (SEQLEN - 1)) * INDIM + (tid & 3)];
    __syncthreads();

    // ---------------- decoder: 320 threads (R12 verbatim, fp32) ----------
    const int dm   = tid >> 2;
    const int dmat = (tid >> 1) & 1;
    const int dkh  = tid & 1;

    #pragma unroll 1
    for (int t = SEQLEN; t < TOT; ++t) {
        float* cur = (t & 1) ? hB : hA;
        float* prv = (t & 1) ? hA : hB;

        #pragma unroll 1
        for (int l = 0; l < LAYERS; ++l) {
            if (tid < 320) {
                float a[4][2];
                #pragma unroll
                for (int j = 0; j < 4; ++j) { a[j][0] = 0.0f; a[j][1] = 0.0f; }

                if (l == 0 && dmat) {
                    if (dkh == 0) {        // W0 . x (both batches)
                        const float4 xv0 = *(const float4*)&sx[0][0];
                        const float4 xv1 = *(const float4*)&sx[1][0];
                        #pragma unroll
                        for (int j = 0; j < 4; ++j) {
                            const float4 w0v = w0d[j * 320 + tid];
                            a[j][0] += w0v.x * xv0.x + w0v.y * xv0.y + w0v.z * xv0.z + w0v.w * xv0.w;
                            a[j][1] += w0v.x * xv1.x + w0v.y * xv1.y + w0v.z * xv1.z + w0v.w * xv1.w;
                        }
                    }
                } else {
                    const float* hb = (dmat ? cur + (l - 1) * LSTR : prv + l * LSTR)
                                      + dkh * 40;
                    const float4* wp = w4d + (size_t)l * 12800 + tid;
                    float4 wv[4];
                    wv[0] = wp[0]; wv[1] = wp[320]; wv[2] = wp[640]; wv[3] = wp[960];

                    #pragma unroll 1
                    for (int i = 0; i < 9; ++i) {
                        const float4* np = wp + 1280;
                        float4 nv[4];
                        nv[0] = np[0]; nv[1] = np[320]; nv[2] = np[640]; nv[3] = np[960];
                        float4 hv[2];
                        hv[0] = *(const float4*)(hb + 4 * i);
                        hv[1] = *(const float4*)(hb + BSTR + 4 * i);
                        FMA8(wv, hv);
                        #pragma unroll
                        for (int j = 0; j < 4; ++j) wv[j] = nv[j];
                        wp = np;
                    }
                    {   // tail i = 9
                        float4 hv[2];
                        hv[0] = *(const float4*)(hb + 36);
                        hv[1] = *(const float4*)(hb + BSTR + 36);
                        FMA8(wv, hv);
                    }
                }

                // fold: k-half (xor1) then mat (xor2)
                float s[4];
                #pragma unroll
                for (int j = 0; j < 4; ++j)
                    s[j] = a[j][dkh] + __shfl_xor(a[j][dkh ^ 1], 1);
                #pragma unroll
                for (int j = 0; j < 4; ++j)
                    s[j] += __shfl_xor(s[j], 2);

                const float4 bv = b4d[l * 80 + dm];
                float act0, act1;
                if (!dmat) { act0 = sigm(s[0] + bv.x);      act1 = sigm(s[1] + bv.y); }
                else       { act0 = tanh_fast(s[2] + bv.z); act1 = sigm(s[3] + bv.w); }
                const float o0 = __shfl_xor(act0, 2);
                const float o1 = __shfl_xor(act1, 2);
                if (!dmat) {
                    const float gi = act0, gf = act1, gg = o0, go = o1;
                    const int ci = l * (ENB * HID) + dkh * HID + dm;
                    const float cn = gf * cS[ci] + gi * gg;
                    cS[ci] = cn;
                    cur[l * LSTR + dkh * BSTR + dm] = go * tanh_fast(cn);
                }
            }
            __syncthreads();
        }

        const int td = t - SEQLEN;
        if (tid < ENB) {                // pred + feedback
            float s = fcb[0];
            const float* hvp = cur + 4 * LSTR + tid * BSTR;
            #pragma unroll
            for (int jj = 0; jj < HID; jj += 4) {
                const float4 wv4 = *(const float4*)&fcW[jj];
                const float4 h4  = *(const float4*)&hvp[jj];
                s += wv4.x * h4.x + wv4.y * h4.y + wv4.z * h4.z + wv4.w * h4.w;
            }
            out[(size_t)(b0 + tid) * PREDLEN + td] = s;
            sx[tid][0] = s;
        } else if (tid >= 64 && tid < 64 + ENB * 3) {
            const int qd = tid - 64;
            const int nb = qd / 3, k = qd % 3;
            sx[nb][k + 1] = ff[((size_t)(b0 + nb) * PREDLEN + td) * 3 + k];
        }
        __syncthreads();
    }
}

// ================= fallback (R5 kernel, proven) if ws too small =================
#define FQK 20
#define FCHUNK(WPTR, HPTR, I)                                                    \
    do {                                                                         \
        const float4 wA = *(const float4*)((WPTR) + 4 * (I));                    \
        const float4 wB = *(const float4*)((WPTR) + HID + 4 * (I));              \
        const float* _hb = (HPTR);                                               \
        const float4 h0 = *(const float4*)(_hb + 0 * HID + 4 * (I));             \
        const float4 h1 = *(const float4*)(_hb + 1 * HID + 4 * (I));             \
        const float4 h2 = *(const float4*)(_hb + 2 * HID + 4 * (I));             \
        const float4 h3 = *(const float4*)(_hb + 3 * HID + 4 * (I));             \
        a00 += wA.x * h0.x + wA.y * h0.y + wA.z * h0.z + wA.w * h0.w;            \
        a01 += wA.x * h1.x + wA.y * h1.y + wA.z * h1.z + wA.w * h1.w;            \
        a02 += wA.x * h2.x + wA.y * h2.y + wA.z * h2.z + wA.w * h2.w;            \
        a03 += wA.x * h3.x + wA.y * h3.y + wA.z * h3.z + wA.w * h3.w;            \
        a10 += wB.x * h0.x + wB.y * h0.y + wB.z * h0.z + wB.w * h0.w;            \
        a11 += wB.x * h1.x + wB.y * h1.y + wB.z * h1.z + wB.w * h1.w;            \
        a12 += wB.x * h2.x + wB.y * h2.y + wB.z * h2.z + wB.w * h2.w;            \
        a13 += wB.x * h3.x + wB.y * h3.y + wB.z * h3.z + wB.w * h3.w;            \
    } while (0)

__global__ __launch_bounds__(640) void lstm_fb(
    const float* __restrict__ x,    const float* __restrict__ ff,
    const float* __restrict__ eW0,  const float* __restrict__ eWih,
    const float* __restrict__ eWhh, const float* __restrict__ ebih,
    const float* __restrict__ ebhh,
    const float* __restrict__ dW0,  const float* __restrict__ dWih,
    const float* __restrict__ dWhh, const float* __restrict__ dbih,
    const float* __restrict__ dbhh,
    const float* __restrict__ fcW,  const float* __restrict__ fcb,
    float* __restrict__ out)
{
    __shared__ __align__(16) float sh[LAYERS][NB][HID];
    __shared__ __align__(16) float sc[LAYERS][NB][HID];
    __shared__ __align__(16) float sg[NB][GATES + 1];
    __shared__ __align__(16) float sx[NB][INDIM];

    const int tid = threadIdx.x;
    const int q   = tid & 3;
    const int mm  = tid >> 2;
    const int r0  = 2 * mm;
    const int b0  = blockIdx.x * NB;

    for (int i = tid; i < LAYERS * NB * HID; i += 640) {
        (&sh[0][0][0])[i] = 0.0f;
        (&sc[0][0][0])[i] = 0.0f;
    }
    const bool is_tg = (r0 >= 2 * HID) && (r0 < 3 * HID);
    const int  unb = tid / HID, uj = tid % HID;

    float bs[2][LAYERS][2];
    #pragma unroll
    for (int l = 0; l < LAYERS; ++l) {
        bs[0][l][0] = ebih[l * GATES + r0]     + ebhh[l * GATES + r0];
        bs[0][l][1] = ebih[l * GATES + r0 + 1] + ebhh[l * GATES + r0 + 1];
        bs[1][l][0] = dbih[l * GATES + r0]     + dbhh[l * GATES + r0];
        bs[1][l][1] = dbih[l * GATES + r0 + 1] + dbhh[l * GATES + r0 + 1];
    }
    const float w0e0 = eW0[r0 * INDIM + q], w0e1 = eW0[(r0 + 1) * INDIM + q];
    const float w0d0 = dW0[r0 * INDIM + q], w0d1 = dW0[(r0 + 1) * INDIM + q];

    for (int t = 0; t < TOT; ++t) {
        const bool enc = (t < SEQLEN);
        const float* Wih = enc ? eWih : dWih;
        const float* Whh = enc ? eWhh : dWhh;
        if (enc && tid < NB * INDIM) {
            const int nb = tid / INDIM, k = tid % INDIM;
            sx[nb][k] = x[((size_t)(b0 + nb) * SEQLEN + t) * INDIM + k];
        }
        __syncthreads();
        #pragma unroll
        for (int l = 0; l < LAYERS; ++l) {
            float a00 = 0.f, a01 = 0.f, a02 = 0.f, a03 = 0.f;
            float a10 = 0.f, a11 = 0.f, a12 = 0.f, a13 = 0.f;
            {
                const float* wp = Whh + ((size_t)l * GATES + r0) * HID + q * FQK;
                const float* hp = &sh[l][0][q * FQK];
                #pragma unroll
                for (int i = 0; i < FQK / 4; ++i) FCHUNK(wp, hp, i);
            }
            if (l == 0) {
                const float wa = enc ? w0e0 : w0d0;
                const float wb = enc ? w0e1 : w0d1;
                a00 += wa * sx[0][q];  a01 += wa * sx[1][q];
                a02 += wa * sx[2][q];  a03 += wa * sx[3][q];
                a10 += wb * sx[0][q];  a11 += wb * sx[1][q];
                a12 += wb * sx[2][q];  a13 += wb * sx[3][q];
            } else {
                const float* wp = Wih + ((size_t)(l - 1) * GATES + r0) * HID + q * FQK;
                const float* hp = &sh[l - 1][0][q * FQK];
                #pragma unroll
                for (int i = 0; i < FQK / 4; ++i) FCHUNK(wp, hp, i);
            }
            const float s0 = rs4(a00, a01, a02, a03, q);
            const float s1 = rs4(a10, a11, a12, a13, q);
            const float bias0 = enc ? bs[0][l][0] : bs[1][l][0];
            const float bias1 = enc ? bs[0][l][1] : bs[1][l][1];
            sg[q][r0]     = gate_act(s0 + bias0, is_tg);
            sg[q][r0 + 1] = gate_act(s1 + bias1, is_tg);
            __syncthreads();
            if (tid < NB * HID) {
                const float iv = sg[unb][uj];
                const float fv = sg[unb][uj + HID];
                const float gv = sg[unb][uj + 2 * HID];
                const float ov = sg[unb][uj + 3 * HID];
                const float cn = fv * sc[l][unb][uj] + iv * gv;
                const float hn = ov * tanh_fast(cn);
                sc[l][unb][uj] = cn;
                sh[l][unb][uj] = hn;
            }
            __syncthreads();
        }
        if (!enc) {
            const int td = t - SEQLEN;
            if (tid < NB) {
                float s = fcb[0];
                #pragma unroll
                for (int j = 0; j < HID; j += 4) {
                    const float4 wv = *(const float4*)&fcW[j];
                    const float4 hv = *(const float4*)&sh[LAYERS - 1][tid][j];
                    s += wv.x * hv.x + wv.y * hv.y + wv.z * hv.z + wv.w * hv.w;
                }
                out[(size_t)(b0 + tid) * PREDLEN + td] = s;
                sx[tid][0] = s;
            } else if (tid >= 64 && tid < 64 + NB * 3) {
                const int qd = tid - 64;
                const int nb = qd / 3, k = qd % 3;
                sx[nb][k + 1] = ff[((size_t)(b0 + nb) * PREDLEN + td) * 3 + k];
            }
        }
    }
}

extern "C" void kernel_launch(void* const* d_in, const int* in_sizes, int n_in,
                              void* d_out, int out_size, void* d_ws, size_t ws_size,
                              hipStream_t stream) {
    const float* x    = (const float*)d_in[0];
    const float* ff   = (const float*)d_in[1];
    const float* eW0  = (const float*)d_in[2];
    const float* eWih = (const float*)d_in[3];
    const float* eWhh = (const float*)d_in[4];
    const float* ebih = (const float*)d_in[5];
    const float* ebhh = (const float*)d_in[6];
    const float* dW0  = (const float*)d_in[7];
    const float* dWih = (const float*)d_in[8];
    const float* dWhh = (const float*)d_in[9];
    const float* dbih = (const float*)d_in[10];
    const float* dbhh = (const float*)d_in[11];
    const float* fcW  = (const float*)d_in[12];
    const float* fcb  = (const float*)d_in[13];

    if (ws_size >= WS_NEED) {
        prep_pack<<<(NPREP + 255) / 256, 256, 0, stream>>>(
            eW0, eWih, eWhh, ebih, ebhh, dW0, dWih, dWhh, dbih, dbhh, (float*)d_ws);
        lstm_main<<<BATCH / ENB, NTHR, 0, stream>>>(
            x, ff, fcW, fcb, (const float*)d_ws, (float*)d_out);
    } else {
        lstm_fb<<<BATCH / NB, 640, 0, stream>>>(
            x, ff, eW0, eWih, eWhh, ebih, ebhh,
            dW0, dWih, dWhh, dbih, dbhh, fcW, fcb, (float*)d_out);
    }
}

// Round 19
// 2508.042 us; speedup vs baseline: 7.5153x; 1.0560x over previous
//
#include <hip/hip_runtime.h>
#include <hip/hip_fp16.h>
#include <math.h>

// Seq2seq LSTM: 5-layer stack, HID=80, 336 enc + 48 dec steps, batch 512.
// R19: R18 (2.65ms) + two BYTE levers (scheduling depth exhausted, 5 nulls):
//   (a) worker-1's full layer weights (fp16, 102.4 KB) cached in LDS at start
//       -> that worker never touches L2; global stream -22%/superstep.
//   (b) decoder weights fp16 via R16's proven fma_mix path (h stays fp32):
//       decoder weight bytes -50%.
//   Encoder dot2 path, wavefront, transition, fallback unchanged.
#define LAYERS  5
#define HID     80
#define GATES   320
#define INDIM   4
#define BATCH   512
#define SEQLEN  336
#define PREDLEN 48
#define TOT     (SEQLEN + PREDLEN)
#define NB      4            // fallback kernel's batch/block
#define ENB     2            // main kernel's batch/block
#define NTHR    800
#define NSUP    (SEQLEN + LAYERS - 1)   // 340 supersteps

#define BSTR 96
#define LSTR (ENB * BSTR)        // 192
#define HTOT (LAYERS * LSTR)     // 960 floats per parity buffer
#define CSZ  (LAYERS * ENB * HID)// 800
#define M16B 48                  // fp16 mirror: uints per batch row (96 halves)
#define M16L (ENB * M16B)        // 96 uints per layer
#define MSZ  (LAYERS * M16L)     // 480 uints per parity mirror

// ws (16B units): [enc-f16 32000][dec-f16 32000][bias_e 400][bias_d 400][w0dec 1280]
//  enc-f16: uint4[((wl*20+i)*2 + p)*160 + lt]  lt=em*2+emat, p=gate-pair
//  dec-f16: uint4[((l*10+i)*2 + p)*320 + lt]   lt=dm*4+dmat*2+dkh, k0=dkh*40+4i
//           gates 2p,2p+1; l==0/dmat==1 slab is zeros (W0 via w0dec fp32)
#define NE16    32000
#define ND16    32000
#define OFF_D   NE16             // 32000
#define OFF_BE  (NE16 + ND16)    // 64000
#define OFF_BD  (OFF_BE + 400)   // 64400
#define OFF_W0D (OFF_BD + 400)   // 64800
#define NWS4    (OFF_W0D + 1280) // 66080
#define WS_NEED ((size_t)NWS4 * 16)
#define NPREP   NWS4

__device__ __forceinline__ float sigm(float v) { return 1.0f / (1.0f + __expf(-v)); }
__device__ __forceinline__ float tanh_fast(float v) {
    return 1.0f - 2.0f / (1.0f + __expf(2.0f * v));
}
__device__ __forceinline__ float gate_act(float v, bool tg) {
    const float e = __expf(tg ? 2.0f * v : -v);
    const float r = 1.0f / (1.0f + e);
    return tg ? 1.0f - 2.0f * r : r;
}
__device__ __forceinline__ float rs4(float v0, float v1, float v2, float v3, int q) {
    float u = (q & 1) ? v1 : v0;
    float s = (q & 1) ? v0 : v1;
    u += __shfl_xor(s, 1);
    float u2 = (q & 1) ? v3 : v2;
    float s2 = (q & 1) ? v2 : v3;
    u2 += __shfl_xor(s2, 1);
    float k = (q & 2) ? u2 : u;
    float s3 = (q & 2) ? u : u2;
    k += __shfl_xor(s3, 2);
    return k;
}

__device__ __forceinline__ unsigned h2bits(__half2 h) {
    union { __half2 h; unsigned u; } c; c.h = h; return c.u;
}

// acc += dot2(f16x2 w, f16x2 h)  -- v_dot2_f32_f16 where available
typedef _Float16 h2v __attribute__((ext_vector_type(2)));
__device__ __forceinline__ float dot2f(unsigned wu, unsigned hu, float acc) {
    union { unsigned u; h2v v; } cw, ch;
    cw.u = wu; ch.u = hu;
#if __has_builtin(__builtin_amdgcn_fdot2)
    return __builtin_amdgcn_fdot2(cw.v, ch.v, acc, false);
#else
    acc = fmaf((float)cw.v[0], (float)ch.v[0], acc);
    return fmaf((float)cw.v[1], (float)ch.v[1], acc);
#endif
}

// fp16 weight x fp32 h, fused cvt (v_fma_mix_f32 pattern) — decoder path
__device__ __forceinline__ void fma_mix4(float& acc, unsigned w01, unsigned w23,
                                         const float4& h) {
    union { unsigned u; __half2 h2; } c01, c23;
    c01.u = w01; c23.u = w23;
    acc = fmaf(__half2float(__low2half(c01.h2)),  h.x, acc);
    acc = fmaf(__half2float(__high2half(c01.h2)), h.y, acc);
    acc = fmaf(__half2float(__low2half(c23.h2)),  h.z, acc);
    acc = fmaf(__half2float(__high2half(c23.h2)), h.w, acc);
}
#define MIXCHUNK(U0, U1, H)                                                      \
    do {                                                                         \
        fma_mix4(a[0][0], (U0).x, (U0).y, (H)[0]);                               \
        fma_mix4(a[0][1], (U0).x, (U0).y, (H)[1]);                               \
        fma_mix4(a[1][0], (U0).z, (U0).w, (H)[0]);                               \
        fma_mix4(a[1][1], (U0).z, (U0).w, (H)[1]);                               \
        fma_mix4(a[2][0], (U1).x, (U1).y, (H)[0]);                               \
        fma_mix4(a[2][1], (U1).x, (U1).y, (H)[1]);                               \
        fma_mix4(a[3][0], (U1).z, (U1).w, (H)[0]);                               \
        fma_mix4(a[3][1], (U1).z, (U1).w, (H)[1]);                               \
    } while (0)

// one k-chunk (k=4): U0/U1 = 4 gates x 2 k-pairs; H[b] = uint2 of 2 k-pairs
#define DOT16(U0, U1, H)                                                         \
    do {                                                                         \
        a[0][0] = dot2f((U0).x, (H)[0].x, a[0][0]);                              \
        a[0][0] = dot2f((U0).y, (H)[0].y, a[0][0]);                              \
        a[0][1] = dot2f((U0).x, (H)[1].x, a[0][1]);                              \
        a[0][1] = dot2f((U0).y, (H)[1].y, a[0][1]);                              \
        a[1][0] = dot2f((U0).z, (H)[0].x, a[1][0]);                              \
        a[1][0] = dot2f((U0).w, (H)[0].y, a[1][0]);                              \
        a[1][1] = dot2f((U0).z, (H)[1].x, a[1][1]);                              \
        a[1][1] = dot2f((U0).w, (H)[1].y, a[1][1]);                              \
        a[2][0] = dot2f((U1).x, (H)[0].x, a[2][0]);                              \
        a[2][0] = dot2f((U1).y, (H)[0].y, a[2][0]);                              \
        a[2][1] = dot2f((U1).x, (H)[1].x, a[2][1]);                              \
        a[2][1] = dot2f((U1).y, (H)[1].y, a[2][1]);                              \
        a[3][0] = dot2f((U1).z, (H)[0].x, a[3][0]);                              \
        a[3][0] = dot2f((U1).w, (H)[0].y, a[3][0]);                              \
        a[3][1] = dot2f((U1).z, (H)[1].x, a[3][1]);                              \
        a[3][1] = dot2f((U1).w, (H)[1].y, a[3][1]);                              \
    } while (0)

// fp16 h pair-load: chunk C (k=4C..4C+3) for both batches from mirror base mb
#define LDH16(SET, C)                                                            \
    do {                                                                         \
        (SET)[0] = *(const uint2*)(mb + 2 * (C));                                \
        (SET)[1] = *(const uint2*)(mb + M16B + 2 * (C));                         \
    } while (0)

// encoder superstep dot body: 4-deep ring over WQ (global or LDS base + lt)
#define ENC_DOT(WQ)                                                              \
    do {                                                                         \
        const uint4* wq = (WQ);                                                  \
        uint4 u0a = wq[0],   u0b = wq[160];                                      \
        uint4 u1a = wq[320], u1b = wq[480];                                      \
        uint4 u2a = wq[640], u2b = wq[800];                                      \
        uint4 u3a = wq[960], u3b = wq[1120];                                     \
        uint2 h0[2], h1[2], h2[2], h3[2];                                        \
        LDH16(h0, 0); LDH16(h1, 1); LDH16(h2, 2); LDH16(h3, 3);                  \
        _Pragma("unroll 1")                                                      \
        for (int q4 = 0; q4 < nquad - 1; ++q4) {                                 \
            const int c = 4 * q4;                                                \
            DOT16(u0a, u0b, h0); u0a = wq[1280]; u0b = wq[1440]; LDH16(h0, c + 4);\
            DOT16(u1a, u1b, h1); u1a = wq[1600]; u1b = wq[1760]; LDH16(h1, c + 5);\
            DOT16(u2a, u2b, h2); u2a = wq[1920]; u2b = wq[2080]; LDH16(h2, c + 6);\
            DOT16(u3a, u3b, h3); u3a = wq[2240]; u3b = wq[2400]; LDH16(h3, c + 7);\
            wq += 1280;                                                          \
        }                                                                        \
        DOT16(u0a, u0b, h0);                                                     \
        DOT16(u1a, u1b, h1);                                                     \
        DOT16(u2a, u2b, h2);                                                     \
        DOT16(u3a, u3b, h3);                                                     \
    } while (0)

// ================= prep: pack weights/biases =================
__global__ void prep_pack(const float* __restrict__ eW0,  const float* __restrict__ eWih,
                          const float* __restrict__ eWhh, const float* __restrict__ ebih,
                          const float* __restrict__ ebhh,
                          const float* __restrict__ dW0,  const float* __restrict__ dWih,
                          const float* __restrict__ dWhh, const float* __restrict__ dbih,
                          const float* __restrict__ dbhh, float* __restrict__ ws)
{
    const int gid = blockIdx.x * 256 + threadIdx.x;
    float4* w4 = (float4*)ws;
    if (gid < NE16) {                   // encoder fp16 layout
        const int lt = gid % 160;
        const int p  = (gid / 160) & 1;
        const int i  = (gid / 320) % 20;
        const int wl = gid / 6400;
        const int m = lt >> 1, mat = lt & 1;
        float4 f[2];
        #pragma unroll
        for (int g = 0; g < 2; ++g) {
            const int j = 2 * p + g;
            const int row = m + 80 * j;
            float4 v = make_float4(0.f, 0.f, 0.f, 0.f);
            if (wl > 0) {
                v = mat ? *(const float4*)&eWih[((size_t)(wl - 1) * GATES + row) * HID + 4 * i]
                        : *(const float4*)&eWhh[((size_t)wl * GATES + row) * HID + 4 * i];
            } else if (!mat) {
                if (i < 10) v = *(const float4*)&eWhh[(size_t)row * HID + 4 * i];
            } else {
                if (i < 10)       v = *(const float4*)&eWhh[(size_t)row * HID + 40 + 4 * i];
                else if (i == 10) v = *(const float4*)&eW0[row * INDIM];
            }
            f[g] = v;
        }
        uint4 u;
        u.x = h2bits(__floats2half2_rn(f[0].x, f[0].y));
        u.y = h2bits(__floats2half2_rn(f[0].z, f[0].w));
        u.z = h2bits(__floats2half2_rn(f[1].x, f[1].y));
        u.w = h2bits(__floats2half2_rn(f[1].z, f[1].w));
        ((uint4*)ws)[gid] = u;
        return;
    }
    int g2 = gid - NE16;
    if (g2 < ND16) {                    // decoder fp16 layout
        const int lt = g2 % 320;
        const int p  = (g2 / 320) & 1;
        const int i  = (g2 / 640) % 10;
        const int l  = g2 / 6400;
        const int dm = lt >> 2, dmat = (lt >> 1) & 1, dkh = lt & 1;
        const int k0 = dkh * 40 + 4 * i;
        float4 f[2];
        #pragma unroll
        for (int g = 0; g < 2; ++g) {
            const int j = 2 * p + g;
            const int row = dm + 80 * j;
            float4 v = make_float4(0.f, 0.f, 0.f, 0.f);
            if (l == 0) {
                if (!dmat) v = *(const float4*)&dWhh[(size_t)row * HID + k0];
            } else {
                v = dmat ? *(const float4*)&dWih[((size_t)(l - 1) * GATES + row) * HID + k0]
                         : *(const float4*)&dWhh[((size_t)l * GATES + row) * HID + k0];
            }
            f[g] = v;
        }
        uint4 u;
        u.x = h2bits(__floats2half2_rn(f[0].x, f[0].y));
        u.y = h2bits(__floats2half2_rn(f[0].z, f[0].w));
        u.z = h2bits(__floats2half2_rn(f[1].x, f[1].y));
        u.w = h2bits(__floats2half2_rn(f[1].z, f[1].w));
        ((uint4*)ws)[OFF_D + g2] = u;
        return;
    }
    int g3 = g2 - ND16;
    if (g3 < 800) {                     // biases: [ctx][l][m] f4 over gates
        const int ctx = g3 / 400, r = g3 % 400;
        const int l = r / 80, m = r % 80;
        const float* bi = ctx ? dbih : ebih;
        const float* bh = ctx ? dbhh : ebhh;
        float4 v;
        v.x = bi[l * GATES + m]       + bh[l * GATES + m];
        v.y = bi[l * GATES + m + 80]  + bh[l * GATES + m + 80];
        v.z = bi[l * GATES + m + 160] + bh[l * GATES + m + 160];
        v.w = bi[l * GATES + m + 240] + bh[l * GATES + m + 240];
        w4[OFF_BE + g3] = v;
        return;
    }
    int g4 = g3 - 800;
    if (g4 < 1280) {                    // decoder W0 rows (fp32)
        const int lt = g4 % 320, j = g4 / 320;
        const int dm = lt >> 2;
        w4[OFF_W0D + g4] = *(const float4*)&dW0[(dm + 80 * j) * INDIM];
    }
}

// ================= main persistent kernel =================
__global__ __launch_bounds__(NTHR, 1) void lstm_main(
    const float* __restrict__ x,   const float* __restrict__ ff,
    const float* __restrict__ fcW, const float* __restrict__ fcb,
    const float* __restrict__ ws,  float* __restrict__ out)
{
    __shared__ __align__(16) uint4 wlds[6400];     // layer-1 enc weights (102.4 KB)
    __shared__ __align__(16) float hA[HTOT];       // parity-0 h (fp32, for dec)
    __shared__ __align__(16) float hB[HTOT];       // parity-1 h
    __shared__ __align__(16) unsigned mA16[MSZ];   // parity-0 fp16 h mirror (+x)
    __shared__ __align__(16) unsigned mB16[MSZ];   // parity-1 fp16 h mirror
    __shared__ __align__(16) float cS[CSZ];
    __shared__ __align__(16) float sx[ENB][4];     // decoder input (fp32)

    const uint4*  w16  = (const uint4*)ws;
    const uint4*  w16d = w16 + OFF_D;
    const float4* b4e  = (const float4*)ws + OFF_BE;
    const float4* b4d  = (const float4*)ws + OFF_BD;
    const float4* w0d  = (const float4*)ws + OFF_W0D;

    const int tid = threadIdx.x;
    const int b0  = blockIdx.x * ENB;

    for (int i = tid; i < 6400; i += NTHR) wlds[i] = w16[6400 + i];  // layer-1 slab
    for (int i = tid; i < HTOT; i += NTHR) { hA[i] = 0.0f; hB[i] = 0.0f; }
    for (int i = tid; i < MSZ;  i += NTHR) { mA16[i] = 0u; mB16[i] = 0u; }
    for (int i = tid; i < CSZ;  i += NTHR) cS[i] = 0.0f;
    if (tid < ENB) {   // prestage x(0) into mB16 x-halves (prv of superstep 0)
        const float4 xv = *(const float4*)&x[((size_t)(b0 + tid) * SEQLEN) * INDIM];
        __half* mx = (__half*)mB16 + (size_t)tid * 96 + 80;
        mx[0] = __float2half(xv.x); mx[1] = __float2half(xv.y);
        mx[2] = __float2half(xv.z); mx[3] = __float2half(xv.w);
    }
    __syncthreads();

    // ---------------- encoder: wavefront supersteps ----------------
    const int wl    = tid / 160;          // layer worker
    const int lt    = tid % 160;
    const int em    = lt >> 1;            // unit
    const int emat  = lt & 1;             // matrix half
    const int nquad = (wl == 0) ? 3 : 5;  // 4-chunk groups; chunks = 4*nquad

    #pragma unroll 1
    for (int s = 0; s < NSUP; ++s) {
        float*    cur  = (s & 1) ? hB : hA;
        unsigned* mcur = (s & 1) ? mB16 : mA16;
        unsigned* mprv = (s & 1) ? mA16 : mB16;
        const int t = s - wl;

        if (tid < ENB && s + 1 < SEQLEN) {  // stage x(s+1) into mcur x-halves
            const float4 xv = *(const float4*)&x[((size_t)(b0 + tid) * SEQLEN + (s + 1)) * INDIM];
            __half* mx = (__half*)mcur + (size_t)tid * 96 + 80;
            mx[0] = __float2half(xv.x); mx[1] = __float2half(xv.y);
            mx[2] = __float2half(xv.z); mx[3] = __float2half(xv.w);
        }

        if (t >= 0 && t < SEQLEN) {
            const unsigned* mb = emat ? (wl ? mprv + (wl - 1) * M16L : mprv + 20)
                                      : mprv + wl * M16L;
            float a[4][2];
            #pragma unroll
            for (int j = 0; j < 4; ++j) { a[j][0] = 0.0f; a[j][1] = 0.0f; }

            if (wl == 1) {
                ENC_DOT(wlds + lt);                        // LDS-cached layer
            } else {
                ENC_DOT(w16 + (size_t)wl * 6400 + lt);     // L2-streamed layers
            }

            // mat fold: lane keeps batch emat
            float sA[4];
            #pragma unroll
            for (int j = 0; j < 4; ++j)
                sA[j] = a[j][emat] + __shfl_xor(a[j][emat ^ 1], 1);

            const float4 bv = b4e[wl * 80 + em];
            const float gi = sigm(sA[0] + bv.x);
            const float gf = sigm(sA[1] + bv.y);
            const float gg = tanh_fast(sA[2] + bv.z);
            const float go = sigm(sA[3] + bv.w);
            const int ci = wl * (ENB * HID) + emat * HID + em;
            const float cn = gf * cS[ci] + gi * gg;
            cS[ci] = cn;
            const float hn = go * tanh_fast(cn);
            cur[wl * LSTR + emat * BSTR + em] = hn;                       // fp32 (dec)
            ((__half*)mcur)[(size_t)(wl * 2 + emat) * 96 + em] = __float2half(hn);
        }
        __syncthreads();
    }

    // ---------------- transition: gather final h into hB; stage dec input ----
    for (int i = tid; i < 2 * LSTR; i += NTHR) {
        const int l = (i < LSTR) ? 1 : 3;
        const int off = i % LSTR;
        hB[l * LSTR + off] = hA[l * LSTR + off];
    }
    if (tid < ENB * INDIM)
        sx[tid >> 2][tid & 3] =
            x[((size_t)(b0 + (tid >> 2)) * SEQLEN + (SEQLEN - 1)) * INDIM + (tid & 3)];
    __syncthreads();

    // ---------------- decoder: 320 threads, fp16 weights via fma_mix ----------
    const int dm   = tid >> 2;
    const int dmat = (tid >> 1) & 1;
    const int dkh  = tid & 1;

    #pragma unroll 1
    for (int t = SEQLEN; t < TOT; ++t) {
        float* cur = (t & 1) ? hB : hA;
        float* prv = (t & 1) ? hA : hB;

        #pragma unroll 1
        for (int l = 0; l < LAYERS; ++l) {
            if (tid < 320) {
                float a[4][2];
                #pragma unroll
                for (int j = 0; j < 4; ++j) { a[j][0] = 0.0f; a[j][1] = 0.0f; }

                if (l == 0 && dmat) {
                    if (dkh == 0) {        // W0 . x (both batches, fp32)
                        const float4 xv0 = *(const float4*)&sx[0][0];
                        const float4 xv1 = *(const float4*)&sx[1][0];
                        #pragma unroll
                        for (int j = 0; j < 4; ++j) {
                            const float4 w0v = w0d[j * 320 + tid];
                            a[j][0] += w0v.x * xv0.x + w0v.y * xv0.y + w0v.z * xv0.z + w0v.w * xv0.w;
                            a[j][1] += w0v.x * xv1.x + w0v.y * xv1.y + w0v.z * xv1.z + w0v.w * xv1.w;
                        }
                    }
                } else {
                    const float* hb = (dmat ? cur + (l - 1) * LSTR : prv + l * LSTR)
                                      + dkh * 40;
                    const uint4* wp = w16d + (size_t)l * 6400 + tid;
                    uint4 u0 = wp[0], u1 = wp[320];

                    #pragma unroll 1
                    for (int i = 0; i < 9; ++i) {
                        const uint4 n0 = wp[640], n1 = wp[960];
                        float4 hv[2];
                        hv[0] = *(const float4*)(hb + 4 * i);
                        hv[1] = *(const float4*)(hb + BSTR + 4 * i);
                        MIXCHUNK(u0, u1, hv);
                        u0 = n0; u1 = n1; wp += 640;
                    }
                    {   // tail i = 9
                        float4 hv[2];
                        hv[0] = *(const float4*)(hb + 36);
                        hv[1] = *(const float4*)(hb + BSTR + 36);
                        MIXCHUNK(u0, u1, hv);
                    }
                }

                // fold: k-half (xor1) then mat (xor2)
                float s[4];
                #pragma unroll
                for (int j = 0; j < 4; ++j)
                    s[j] = a[j][dkh] + __shfl_xor(a[j][dkh ^ 1], 1);
                #pragma unroll
                for (int j = 0; j < 4; ++j)
                    s[j] += __shfl_xor(s[j], 2);

                const float4 bv = b4d[l * 80 + dm];
                float act0, act1;
                if (!dmat) { act0 = sigm(s[0] + bv.x);      act1 = sigm(s[1] + bv.y); }
                else       { act0 = tanh_fast(s[2] + bv.z); act1 = sigm(s[3] + bv.w); }
                const float o0 = __shfl_xor(act0, 2);
                const float o1 = __shfl_xor(act1, 2);
                if (!dmat) {
                    const float gi = act0, gf = act1, gg = o0, go = o1;
                    const int ci = l * (ENB * HID) + dkh * HID + dm;
                    const float cn = gf * cS[ci] + gi * gg;
                    cS[ci] = cn;
                    cur[l * LSTR + dkh * BSTR + dm] = go * tanh_fast(cn);
                }
            }
            __syncthreads();
        }

        const int td = t - SEQLEN;
        if (tid < ENB) {                // pred + feedback
            float s = fcb[0];
            const float* hvp = cur + 4 * LSTR + tid * BSTR;
            #pragma unroll
            for (int jj = 0; jj < HID; jj += 4) {
                const float4 wv4 = *(const float4*)&fcW[jj];
                const float4 h4  = *(const float4*)&hvp[jj];
                s += wv4.x * h4.x + wv4.y * h4.y + wv4.z * h4.z + wv4.w * h4.w;
            }
            out[(size_t)(b0 + tid) * PREDLEN + td] = s;
            sx[tid][0] = s;
        } else if (tid >= 64 && tid < 64 + ENB * 3) {
            const int qd = tid - 64;
            const int nb = qd / 3, k = qd % 3;
            sx[nb][k + 1] = ff[((size_t)(b0 + nb) * PREDLEN + td) * 3 + k];
        }
        __syncthreads();
    }
}

// ================= fallback (R5 kernel, proven) if ws too small =================
#define FQK 20
#define FCHUNK(WPTR, HPTR, I)                                                    \
    do {                                                                         \
        const float4 wA = *(const float4*)((WPTR) + 4 * (I));                    \
        const float4 wB = *(const float4*)((WPTR) + HID + 4 * (I));              \
        const float* _hb = (HPTR);                                               \
        const float4 h0 = *(const float4*)(_hb + 0 * HID + 4 * (I));             \
        const float4 h1 = *(const float4*)(_hb + 1 * HID + 4 * (I));             \
        const float4 h2 = *(const float4*)(_hb + 2 * HID + 4 * (I));             \
        const float4 h3 = *(const float4*)(_hb + 3 * HID + 4 * (I));             \
        a00 += wA.x * h0.x + wA.y * h0.y + wA.z * h0.z + wA.w * h0.w;            \
        a01 += wA.x * h1.x + wA.y * h1.y + wA.z * h1.z + wA.w * h1.w;            \
        a02 += wA.x * h2.x + wA.y * h2.y + wA.z * h2.z + wA.w * h2.w;            \
        a03 += wA.x * h3.x + wA.y * h3.y + wA.z * h3.z + wA.w * h3.w;            \
        a10 += wB.x * h0.x + wB.y * h0.y + wB.z * h0.z + wB.w * h0.w;            \
        a11 += wB.x * h1.x + wB.y * h1.y + wB.z * h1.z + wB.w * h1.w;            \
        a12 += wB.x * h2.x + wB.y * h2.y + wB.z * h2.z + wB.w * h2.w;            \
        a13 += wB.x * h3.x + wB.y * h3.y + wB.z * h3.z + wB.w * h3.w;            \
    } while (0)

__global__ __launch_bounds__(640) void lstm_fb(
    const float* __restrict__ x,    const float* __restrict__ ff,
    const float* __restrict__ eW0,  const float* __restrict__ eWih,
    const float* __restrict__ eWhh, const float* __restrict__ ebih,
    const float* __restrict__ ebhh,
    const float* __restrict__ dW0,  const float* __restrict__ dWih,
    const float* __restrict__ dWhh, const float* __restrict__ dbih,
    const float* __restrict__ dbhh,
    const float* __restrict__ fcW,  const float* __restrict__ fcb,
    float* __restrict__ out)
{
    __shared__ __align__(16) float sh[LAYERS][NB][HID];
    __shared__ __align__(16) float sc[LAYERS][NB][HID];
    __shared__ __align__(16) float sg[NB][GATES + 1];
    __shared__ __align__(16) float sx[NB][INDIM];

    const int tid = threadIdx.x;
    const int q   = tid & 3;
    const int mm  = tid >> 2;
    const int r0  = 2 * mm;
    const int b0  = blockIdx.x * NB;

    for (int i = tid; i < LAYERS * NB * HID; i += 640) {
        (&sh[0][0][0])[i] = 0.0f;
        (&sc[0][0][0])[i] = 0.0f;
    }
    const bool is_tg = (r0 >= 2 * HID) && (r0 < 3 * HID);
    const int  unb = tid / HID, uj = tid % HID;

    float bs[2][LAYERS][2];
    #pragma unroll
    for (int l = 0; l < LAYERS; ++l) {
        bs[0][l][0] = ebih[l * GATES + r0]     + ebhh[l * GATES + r0];
        bs[0][l][1] = ebih[l * GATES + r0 + 1] + ebhh[l * GATES + r0 + 1];
        bs[1][l][0] = dbih[l * GATES + r0]     + dbhh[l * GATES + r0];
        bs[1][l][1] = dbih[l * GATES + r0 + 1] + dbhh[l * GATES + r0 + 1];
    }
    const float w0e0 = eW0[r0 * INDIM + q], w0e1 = eW0[(r0 + 1) * INDIM + q];
    const float w0d0 = dW0[r0 * INDIM + q], w0d1 = dW0[(r0 + 1) * INDIM + q];

    for (int t = 0; t < TOT; ++t) {
        const bool enc = (t < SEQLEN);
        const float* Wih = enc ? eWih : dWih;
        const float* Whh = enc ? eWhh : dWhh;
        if (enc && tid < NB * INDIM) {
            const int nb = tid / INDIM, k = tid % INDIM;
            sx[nb][k] = x[((size_t)(b0 + nb) * SEQLEN + t) * INDIM + k];
        }
        __syncthreads();
        #pragma unroll
        for (int l = 0; l < LAYERS; ++l) {
            float a00 = 0.f, a01 = 0.f, a02 = 0.f, a03 = 0.f;
            float a10 = 0.f, a11 = 0.f, a12 = 0.f, a13 = 0.f;
            {
                const float* wp = Whh + ((size_t)l * GATES + r0) * HID + q * FQK;
                const float* hp = &sh[l][0][q * FQK];
                #pragma unroll
                for (int i = 0; i < FQK / 4; ++i) FCHUNK(wp, hp, i);
            }
            if (l == 0) {
                const float wa = enc ? w0e0 : w0d0;
                const float wb = enc ? w0e1 : w0d1;
                a00 += wa * sx[0][q];  a01 += wa * sx[1][q];
                a02 += wa * sx[2][q];  a03 += wa * sx[3][q];
                a10 += wb * sx[0][q];  a11 += wb * sx[1][q];
                a12 += wb * sx[2][q];  a13 += wb * sx[3][q];
            } else {
                const float* wp = Wih + ((size_t)(l - 1) * GATES + r0) * HID + q * FQK;
                const float* hp = &sh[l - 1][0][q * FQK];
                #pragma unroll
                for (int i = 0; i < FQK / 4; ++i) FCHUNK(wp, hp, i);
            }
            const float s0 = rs4(a00, a01, a02, a03, q);
            const float s1 = rs4(a10, a11, a12, a13, q);
            const float bias0 = enc ? bs[0][l][0] : bs[1][l][0];
            const float bias1 = enc ? bs[0][l][1] : bs[1][l][1];
            sg[q][r0]     = gate_act(s0 + bias0, is_tg);
            sg[q][r0 + 1] = gate_act(s1 + bias1, is_tg);
            __syncthreads();
            if (tid < NB * HID) {
                const float iv = sg[unb][uj];
                const float fv = sg[unb][uj + HID];
                const float gv = sg[unb][uj + 2 * HID];
                const float ov = sg[unb][uj + 3 * HID];
                const float cn = fv * sc[l][unb][uj] + iv * gv;
                const float hn = ov * tanh_fast(cn);
                sc[l][unb][uj] = cn;
                sh[l][unb][uj] = hn;
            }
            __syncthreads();
        }
        if (!enc) {
            const int td = t - SEQLEN;
            if (tid < NB) {
                float s = fcb[0];
                #pragma unroll
                for (int j = 0; j < HID; j += 4) {
                    const float4 wv = *(const float4*)&fcW[j];
                    const float4 hv = *(const float4*)&sh[LAYERS - 1][tid][j];
                    s += wv.x * hv.x + wv.y * hv.y + wv.z * hv.z + wv.w * hv.w;
                }
                out[(size_t)(b0 + tid) * PREDLEN + td] = s;
                sx[tid][0] = s;
            } else if (tid >= 64 && tid < 64 + NB * 3) {
                const int qd = tid - 64;
                const int nb = qd / 3, k = qd % 3;
                sx[nb][k + 1] = ff[((size_t)(b0 + nb) * PREDLEN + td) * 3 + k];
            }
        }
    }
}

extern "C" void kernel_launch(void* const* d_in, const int* in_sizes, int n_in,
                              void* d_out, int out_size, void* d_ws, size_t ws_size,
                              hipStream_t stream) {
    const float* x    = (const float*)d_in[0];
    const float* ff   = (const float*)d_in[1];
    const float* eW0  = (const float*)d_in[2];
    const float* eWih = (const float*)d_in[3];
    const float* eWhh = (const float*)d_in[4];
    const float* ebih = (const float*)d_in[5];
    const float* ebhh = (const float*)d_in[6];
    const float* dW0  = (const float*)d_in[7];
    const float* dWih = (const float*)d_in[8];
    const float* dWhh = (const float*)d_in[9];
    const float* dbih = (const float*)d_in[10];
    const float* dbhh = (const float*)d_in[11];
    const float* fcW  = (const float*)d_in[12];
    const float* fcb  = (const float*)d_in[13];

    if (ws_size >= WS_NEED) {
        prep_pack<<<(NPREP + 255) / 256, 256, 0, stream>>>(
            eW0, eWih, eWhh, ebih, ebhh, dW0, dWih, dWhh, dbih, dbhh, (float*)d_ws);
        lstm_main<<<BATCH / ENB, NTHR, 0, stream>>>(
            x, ff, fcW, fcb, (const float*)d_ws, (float*)d_out);
    } else {
        lstm_fb<<<BATCH / NB, 640, 0, stream>>>(
            x, ff, eW0, eWih, eWhh, ebih, ebhh,
            dW0, dWih, dWhh, dbih, dbhh, fcW, fcb, (float*)d_out);
    }
}